// Round 10
// baseline (831.370 us; speedup 1.0000x reference)
//
#include <hip/hip_runtime.h>
#include <hip/hip_bf16.h>

// Problem constants
#define BB_ 2
#define SS_ 1024
#define FIN_ 64
#define EE_ 256
#define FF_ 1024
#define NH_ 8
#define HD_ 32
#define OUT_ 10
#define NWIN (BB_ * SS_)
#define NT 512
#define SCALE_ 0.17677669529663687f  // 1/sqrt(32)
#define XBP 264                      // bf16 A-operand pitch (halfwords)
#define TPAD 1088                    // padded token rows per batch (64 pad + 1024)

typedef unsigned short u16;
typedef unsigned int u32;
typedef __attribute__((ext_vector_type(8))) short bf8_t;   // 8 x bf16 (4 VGPRs)
typedef __attribute__((ext_vector_type(4))) float f4_t;    // MFMA C/D
#define MFMA_B16(a, b, c) __builtin_amdgcn_mfma_f32_16x16x32_bf16(a, b, c, 0, 0, 0)

__device__ __forceinline__ u16 bf16r(float f) {
    u32 u = __builtin_bit_cast(u32, f);
    return (u16)((u + 0x7FFFu + ((u >> 16) & 1u)) >> 16);
}
__device__ __forceinline__ u32 pk_bf16(float a, float b) {
    return (u32)bf16r(a) | ((u32)bf16r(b) << 16);
}
__device__ __forceinline__ float b2f(u16 h) {
    return __builtin_bit_cast(float, ((u32)h) << 16);
}
__device__ __forceinline__ float b2f_lo(u32 u) {
    return __builtin_bit_cast(float, u << 16);
}
__device__ __forceinline__ float b2f_hi(u32 u) {
    return __builtin_bit_cast(float, u & 0xFFFF0000u);
}

__device__ __forceinline__ float dot4(float4 a, float4 b) {
    return a.x * b.x + a.y * b.y + a.z * b.z + a.w * b.w;
}
__device__ __forceinline__ float wsum(float v) {
#pragma unroll
    for (int o = 32; o > 0; o >>= 1) v += __shfl_xor(v, o, 64);
    return v;
}
__device__ __forceinline__ float wmax(float v) {
#pragma unroll
    for (int o = 32; o > 0; o >>= 1) v = fmaxf(v, __shfl_xor(v, o, 64));
    return v;
}
__device__ __forceinline__ float silu_f(float h) { return h / (1.f + __expf(-h)); }

// ---------------------------------------------------------------------------
// k_pre: fused (a) embed GEMM  (b) fp32->bf16 weight cvt  (c) qkv bias pads
// ---------------------------------------------------------------------------
struct CvtArgs {
    const float* s[9];
    u16* d[9];
    int n[9];
};

__global__ void k_pre(const float* __restrict__ in, const float* __restrict__ embw,
                      const float* __restrict__ embb, const float* __restrict__ qkv_b,
                      CvtArgs ca, float* __restrict__ emb, u16* __restrict__ qkvp) {
    __shared__ float row[FIN_];
    const int blk = blockIdx.x;
    const int tid = threadIdx.x;
    if (blk < 2048) {            // ---- embed: one token per block
        if (tid < FIN_) row[tid] = in[blk * FIN_ + tid];
        __syncthreads();
        const float4* w4 = (const float4*)(embw + tid * FIN_);
        const float4* r4 = (const float4*)row;
        float s = 0.f;
#pragma unroll
        for (int c = 0; c < FIN_ / 4; ++c) s += dot4(w4[c], r4[c]);
        emb[blk * EE_ + tid] = s + embb[tid];
    } else if (blk < 2816) {     // ---- weight conversion (768 blocks, grid-stride)
        const int b2 = blk - 2048;
#pragma unroll 1
        for (int seg = 0; seg < 9; ++seg) {
            const float* __restrict__ src = ca.s[seg];
            u16* __restrict__ dst = ca.d[seg];
            const int nn = ca.n[seg];
            for (int i = b2 * 256 + tid; i < nn; i += 768 * 256)
                dst[i] = bf16r(src[i]);
        }
    } else {                     // ---- qkv pad rows: qkvp[bat][0..63][j] = bias[j]
        const int b3 = blk - 2816;
        for (int f = b3 * 256 + tid; f < 2 * 64 * 768; f += 8 * 256) {
            const int bat = f / 49152;
            const int rem = f - bat * 49152;
            const int r = rem / 768, cl = rem - r * 768;
            qkvp[((size_t)bat * TPAD + r) * 768 + cl] = bf16r(qkv_b[cl]);
        }
    }
}

// ---------------------------------------------------------------------------
// k_qkv0m (MFMA): qkvp[bb][t+64][j] = bf16(emb[t,:] @ qkv_w0[j,:] + b[j])
// ---------------------------------------------------------------------------
__global__ __launch_bounds__(512) void k_qkv0m(const float* __restrict__ emb,
                                               const u16* __restrict__ wq0b,
                                               const float* __restrict__ qkvb,
                                               u16* __restrict__ qkvp) {
    __shared__ u16 ab[16 * XBP];
    const int b = blockIdx.x;
    const int tid = threadIdx.x, lane = tid & 63, wv = tid >> 6;
    const int col = lane & 15, quad = lane >> 4;
    for (int idx = tid; idx < 16 * 256; idx += 512) {
        const int i = idx >> 8, e = idx & 255;
        ab[i * XBP + e] = bf16r(emb[(b * 16 + i) * EE_ + e]);
    }
    __syncthreads();
    f4_t acc[6];
#pragma unroll
    for (int nt = 0; nt < 6; ++nt) acc[nt] = (f4_t){0.f, 0.f, 0.f, 0.f};
#pragma unroll
    for (int ks = 0; ks < 8; ++ks) {
        const bf8_t ax = *(const bf8_t*)(ab + col * XBP + ks * 32 + quad * 8);
#pragma unroll
        for (int nt = 0; nt < 6; ++nt) {
            const int r = wv * 96 + nt * 16 + col;
            const bf8_t bw = *(const bf8_t*)(wq0b + r * EE_ + ks * 32 + quad * 8);
            acc[nt] = MFMA_B16(ax, bw, acc[nt]);
        }
    }
#pragma unroll
    for (int nt = 0; nt < 6; ++nt) {
        const int cc = wv * 96 + nt * 16 + col;
        const float bs = qkvb[cc];
#pragma unroll
        for (int j = 0; j < 4; ++j) {
            const int tok = b * 16 + quad * 4 + j;
            const int bb = tok >> 10;
            const size_t ti = (size_t)bb * TPAD + (tok & 1023) + 64;
            qkvp[ti * 768 + cc] = bf16r(acc[nt][j] + bs);
        }
    }
}

// ---------------------------------------------------------------------------
// Shared register-LN helper over C-frag-layout state x[ntl][mt][j].
// ---------------------------------------------------------------------------
__device__ __forceinline__ void reg_ln(float (&x)[2][4][4], float* red, float* stat,
                                       u16* xb,
                                       float gc0, float gc1, float bc0, float bc1,
                                       int tid, int wv, int col, int quad,
                                       int colg0, int colg1) {
    float ps[4][4], pq[4][4];
#pragma unroll
    for (int mt = 0; mt < 4; ++mt)
#pragma unroll
        for (int j = 0; j < 4; ++j) {
            const float v0 = x[0][mt][j], v1 = x[1][mt][j];
            ps[mt][j] = v0 + v1;
            pq[mt][j] = v0 * v0 + v1 * v1;
        }
#pragma unroll
    for (int o = 1; o < 16; o <<= 1) {
#pragma unroll
        for (int mt = 0; mt < 4; ++mt)
#pragma unroll
            for (int j = 0; j < 4; ++j) {
                ps[mt][j] += __shfl_xor(ps[mt][j], o);
                pq[mt][j] += __shfl_xor(pq[mt][j], o);
            }
    }
    if (col == 0) {
#pragma unroll
        for (int mt = 0; mt < 4; ++mt)
#pragma unroll
            for (int j = 0; j < 4; ++j) {
                const int row = mt * 16 + quad * 4 + j;
                red[row * 17 + wv * 2] = ps[mt][j];
                red[row * 17 + wv * 2 + 1] = pq[mt][j];
            }
    }
    __syncthreads();
    if (tid < 64) {
        float s = 0.f, q = 0.f;
#pragma unroll
        for (int w = 0; w < 8; ++w) {
            s += red[tid * 17 + w * 2];
            q += red[tid * 17 + w * 2 + 1];
        }
        const float m = s * 0.00390625f;
        const float var = q * 0.00390625f - m * m;
        stat[tid * 2] = m;
        stat[tid * 2 + 1] = rsqrtf(var + 1e-5f);
    }
    __syncthreads();
#pragma unroll
    for (int mt = 0; mt < 4; ++mt)
#pragma unroll
        for (int j = 0; j < 4; ++j) {
            const int row = mt * 16 + quad * 4 + j;
            const float m = stat[row * 2];
            const float rs = stat[row * 2 + 1];
            const float xn0 = (x[0][mt][j] - m) * rs * gc0 + bc0;
            const float xn1 = (x[1][mt][j] - m) * rs * gc1 + bc1;
            x[0][mt][j] = xn0;
            x[1][mt][j] = xn1;
            const u32 w = pk_bf16(xn0, xn1);
            xb[row * XBP + colg0] = (u16)w;
            xb[row * XBP + colg1] = (u16)(w >> 16);
        }
}

// ---------------------------------------------------------------------------
// k_attn: attention + deferred proj + residual + LN1 -> xbg (bf16, global)
// ---------------------------------------------------------------------------
struct __align__(16) SMemA {
    union {
        struct { u16 qkpb[9216]; u16 vt[4608]; u16 pb[9216]; } att;  // 46,080 B
        struct { float red[64 * 17]; float stat[128]; } ln;          //  4,864 B
    } r1;
    u16 obxb[64 * XBP];   // O (attn) then xb (post-LN1)             // 33,792 B
};

__global__ __launch_bounds__(NT, 4) void k_attn(
    const float* __restrict__ emb, const u16* __restrict__ qkvp,
    const u16* __restrict__ wob, const float* __restrict__ aob,
    const float* __restrict__ ln1g, const float* __restrict__ ln1b,
    u16* __restrict__ xbg) {
    __shared__ SMemA sm;
    const int n = blockIdx.x;
    const int bb = n >> 10, p = n & 1023;
    const int tid = threadIdx.x;
    const int lane = tid & 63, wv = tid >> 6;
    const int col = lane & 15, quad = lane >> 4;
    const int colg0 = wv * 32 + col, colg1 = colg0 + 16;

    for (int hp = 0; hp < 4; ++hp) {
        {   // gather: q,k row-major (uint4), v transposed
            const int i = tid >> 3, dg = tid & 7;
            const size_t rb = ((size_t)bb * TPAD + (p + 1 + i)) * 768 + hp * 64 + dg * 8;
            const uint4 q4 = *(const uint4*)(qkvp + rb);
            const uint4 k4 = *(const uint4*)(qkvp + rb + 256);
            const uint4 v4 = *(const uint4*)(qkvp + rb + 512);
            *(uint4*)(sm.r1.att.qkpb + i * 72 + dg * 8) = q4;
            *(uint4*)(sm.r1.att.qkpb + 4608 + i * 72 + dg * 8) = k4;
            union { uint4 u; u16 h[8]; } vu; vu.u = v4;
#pragma unroll
            for (int c = 0; c < 8; ++c)
                sm.r1.att.vt[(dg * 8 + c) * 72 + i] = vu.h[c];
        }
        __syncthreads();   // A: gather visible
        const int hh = wv >> 2, mt_ = wv & 3;
        const int r0 = mt_ * 16 + quad * 4;
        // scores MFMA + in-register softmax
        const bf8_t aq = *(const bf8_t*)(sm.r1.att.qkpb + (mt_ * 16 + col) * 72 + hh * 32 + quad * 8);
        f4_t sc[4];
#pragma unroll
        for (int nt = 0; nt < 4; ++nt) {
            const bf8_t bk = *(const bf8_t*)(sm.r1.att.qkpb + 4608 + (nt * 16 + col) * 72 + hh * 32 + quad * 8);
            f4_t z = {0.f, 0.f, 0.f, 0.f};
            sc[nt] = MFMA_B16(aq, bk, z);
        }
#pragma unroll
        for (int j = 0; j < 4; ++j) {
            float s0 = sc[0][j] * SCALE_, s1 = sc[1][j] * SCALE_;
            float s2v = sc[2][j] * SCALE_, s3 = sc[3][j] * SCALE_;
            float m = fmaxf(fmaxf(s0, s1), fmaxf(s2v, s3));
            m = fmaxf(m, __shfl_xor(m, 1)); m = fmaxf(m, __shfl_xor(m, 2));
            m = fmaxf(m, __shfl_xor(m, 4)); m = fmaxf(m, __shfl_xor(m, 8));
            const float e0 = __expf(s0 - m), e1 = __expf(s1 - m);
            const float e2 = __expf(s2v - m), e3 = __expf(s3 - m);
            float s = e0 + e1 + e2 + e3;
            s += __shfl_xor(s, 1); s += __shfl_xor(s, 2);
            s += __shfl_xor(s, 4); s += __shfl_xor(s, 8);
            const float inv = 1.f / s;
            sc[0][j] = e0 * inv; sc[1][j] = e1 * inv;
            sc[2][j] = e2 * inv; sc[3][j] = e3 * inv;
        }
        // write P to its own buffer (own-wave rows only -> no barrier needed)
        u16* pbh = sm.r1.att.pb + hh * 4608;
#pragma unroll
        for (int nt = 0; nt < 4; ++nt) {
            const u32 w01 = pk_bf16(sc[nt][0], sc[nt][1]);
            const u32 w23 = pk_bf16(sc[nt][2], sc[nt][3]);
            u16* pp = pbh + r0 * 72 + nt * 16 + col;
            pp[0] = (u16)w01; pp[72] = (u16)(w01 >> 16);
            pp[144] = (u16)w23; pp[216] = (u16)(w23 >> 16);
        }
        // PV (same-wave P rows; vt stable)
        f4_t ov[2];
        ov[0] = (f4_t){0.f, 0.f, 0.f, 0.f}; ov[1] = (f4_t){0.f, 0.f, 0.f, 0.f};
#pragma unroll
        for (int ks = 0; ks < 2; ++ks) {
            const bf8_t ap = *(const bf8_t*)(pbh + (mt_ * 16 + col) * 72 + ks * 32 + quad * 8);
#pragma unroll
            for (int ntl = 0; ntl < 2; ++ntl) {
                const bf8_t bv = *(const bf8_t*)(sm.r1.att.vt +
                                                 (hh * 32 + ntl * 16 + col) * 72 + ks * 32 + quad * 8);
                ov[ntl] = MFMA_B16(ap, bv, ov[ntl]);
            }
        }
        // O -> full-width ob
#pragma unroll
        for (int ntl = 0; ntl < 2; ++ntl) {
            const u32 w01 = pk_bf16(ov[ntl][0], ov[ntl][1]);
            const u32 w23 = pk_bf16(ov[ntl][2], ov[ntl][3]);
            u16* oo = sm.obxb + r0 * XBP + (hp * 2 + hh) * 32 + ntl * 16 + col;
            oo[0] = (u16)w01; oo[XBP] = (u16)(w01 >> 16);
            oo[2 * XBP] = (u16)w23; oo[3 * XBP] = (u16)(w23 >> 16);
        }
        __syncthreads();   // C: q/k/vt reads done before next gather overwrites
    }

    // single proj GEMM: pacc = O @ Wo^T  (K = 256)
    f4_t pacc[2][4];
#pragma unroll
    for (int a = 0; a < 2; ++a)
#pragma unroll
        for (int m = 0; m < 4; ++m) pacc[a][m] = (f4_t){0.f, 0.f, 0.f, 0.f};
#pragma unroll 2
    for (int ks = 0; ks < 8; ++ks) {
        bf8_t ao[4];
#pragma unroll
        for (int mt = 0; mt < 4; ++mt)
            ao[mt] = *(const bf8_t*)(sm.obxb + (mt * 16 + col) * XBP + ks * 32 + quad * 8);
#pragma unroll
        for (int ntl = 0; ntl < 2; ++ntl) {
            const bf8_t bw = *(const bf8_t*)(wob + ((wv * 2 + ntl) * 16 + col) * EE_ +
                                             ks * 32 + quad * 8);
#pragma unroll
            for (int mt = 0; mt < 4; ++mt) pacc[ntl][mt] = MFMA_B16(ao[mt], bw, pacc[ntl][mt]);
        }
    }

    // combine x0 + attn + bias, LN1 -> xb in LDS
    const float aob_0 = aob[colg0], aob_1 = aob[colg1];
    float x[2][4][4];
#pragma unroll
    for (int mt = 0; mt < 4; ++mt)
#pragma unroll
        for (int j = 0; j < 4; ++j) {
            const int row = mt * 16 + quad * 4 + j;
            const int t = p - 63 + row;
            const size_t base = (size_t)((bb << 10) + t) * EE_;
            const float e0 = (t >= 0) ? emb[base + colg0] : 0.f;
            const float e1 = (t >= 0) ? emb[base + colg1] : 0.f;
            x[0][mt][j] = e0 + aob_0 + pacc[0][mt][j];
            x[1][mt][j] = e1 + aob_1 + pacc[1][mt][j];
        }
    __syncthreads();   // proj reads of ob done
    reg_ln(x, sm.r1.ln.red, sm.r1.ln.stat, sm.obxb,
           ln1g[colg0], ln1g[colg1], ln1b[colg0], ln1b[colg1],
           tid, wv, col, quad, colg0, colg1);
    __syncthreads();
    // coalesced copy-out: LDS xb (pitch 264) -> global (packed 256/row)
    u16* dst = xbg + (size_t)n * 64 * 256;
#pragma unroll
    for (int k = 0; k < 4; ++k) {
        const int idx = tid + k * NT;
        const int row = idx >> 5, seg = idx & 31;
        *(uint4*)(dst + row * 256 + seg * 8) = *(const uint4*)(sm.obxb + row * XBP + seg * 8);
    }
}

// ---------------------------------------------------------------------------
// k_ffn: FFN (double-buffered hb) + LN2; x1 written back IN PLACE to xbg.
// 2048 blocks x 512. LDS ~68.6 KB (2 blk/CU). FFN-only live set -> no spill.
// ---------------------------------------------------------------------------
struct __align__(16) SMemF {
    u16 xb[64 * XBP];                                            // 33,792 B
    union {
        u16 hb2[2][64 * 136];                                    // 34,816 B
        struct { float red[64 * 17]; float stat[128]; } ln;      //  4,864 B
    } c;
};

__global__ __launch_bounds__(NT, 4) void k_ffn(
    u16* __restrict__ xbg,
    const u16* __restrict__ w1b, const u16* __restrict__ w2b,
    const float* __restrict__ f1b, const float* __restrict__ f2b,
    const float* __restrict__ ln2g, const float* __restrict__ ln2b) {
    __shared__ SMemF sm;
    const int n = blockIdx.x;
    const int tid = threadIdx.x;
    const int lane = tid & 63, wv = tid >> 6;
    const int col = lane & 15, quad = lane >> 4;
    const int colg0 = wv * 32 + col, colg1 = colg0 + 16;

    // load xb: global (packed) -> LDS (pitched)
    u16* gptr = xbg + (size_t)n * 64 * 256;
#pragma unroll
    for (int k = 0; k < 4; ++k) {
        const int idx = tid + k * NT;
        const int row = idx >> 5, seg = idx & 31;
        *(uint4*)(sm.xb + row * XBP + seg * 8) = *(const uint4*)(gptr + row * 256 + seg * 8);
    }
    __syncthreads();

    f4_t facc[2][4];
#pragma unroll
    for (int a = 0; a < 2; ++a)
#pragma unroll
        for (int m = 0; m < 4; ++m) facc[a][m] = (f4_t){0.f, 0.f, 0.f, 0.f};

    auto ffn1_step = [&](int c) {
        f4_t hacc[4];
#pragma unroll
        for (int m = 0; m < 4; ++m) hacc[m] = (f4_t){0.f, 0.f, 0.f, 0.f};
        const int f = c * 128 + wv * 16 + col;
#pragma unroll 2
        for (int ks = 0; ks < 8; ++ks) {
            const bf8_t bw = *(const bf8_t*)(w1b + f * EE_ + ks * 32 + quad * 8);
#pragma unroll
            for (int mt = 0; mt < 4; ++mt) {
                const bf8_t axr = *(const bf8_t*)(sm.xb + (mt * 16 + col) * XBP + ks * 32 + quad * 8);
                hacc[mt] = MFMA_B16(axr, bw, hacc[mt]);
            }
        }
        const float bv = f1b[f];
        const int lc = wv * 16 + col;
        u16* hbc = sm.c.hb2[c & 1];
#pragma unroll
        for (int mt = 0; mt < 4; ++mt) {
            const u32 w01 = pk_bf16(silu_f(hacc[mt][0] + bv), silu_f(hacc[mt][1] + bv));
            const u32 w23 = pk_bf16(silu_f(hacc[mt][2] + bv), silu_f(hacc[mt][3] + bv));
            u16* hh2 = hbc + (mt * 16 + quad * 4) * 136 + lc;
            hh2[0] = (u16)w01; hh2[136] = (u16)(w01 >> 16);
            hh2[272] = (u16)w23; hh2[408] = (u16)(w23 >> 16);
        }
    };
    auto ffn2_step = [&](int c) {
        const u16* hbc = sm.c.hb2[c & 1];
#pragma unroll 2
        for (int ks = 0; ks < 4; ++ks) {
            bf8_t ah[4];
#pragma unroll
            for (int mt = 0; mt < 4; ++mt)
                ah[mt] = *(const bf8_t*)(hbc + (mt * 16 + col) * 136 + ks * 32 + quad * 8);
#pragma unroll
            for (int ntl = 0; ntl < 2; ++ntl) {
                const int e = (wv * 2 + ntl) * 16 + col;
                const bf8_t bw = *(const bf8_t*)(w2b + e * FF_ + c * 128 + ks * 32 + quad * 8);
#pragma unroll
                for (int mt = 0; mt < 4; ++mt) facc[ntl][mt] = MFMA_B16(ah[mt], bw, facc[ntl][mt]);
            }
        }
    };

    ffn1_step(0);
    __syncthreads();
#pragma unroll 1
    for (int c = 0; c < 8; ++c) {
        if (c < 7) ffn1_step(c + 1);   // writes hb2[(c+1)&1]
        ffn2_step(c);                  // reads  hb2[c&1]
        __syncthreads();
    }

    // reconstruct x from bf16 xb, add FFN2 + bias, LN2 -> x1 (into xb)
    const float f2b_0 = f2b[colg0], f2b_1 = f2b[colg1];
    float x[2][4][4];
#pragma unroll
    for (int mt = 0; mt < 4; ++mt)
#pragma unroll
        for (int j = 0; j < 4; ++j) {
            const int row = mt * 16 + quad * 4 + j;
            x[0][mt][j] = b2f(sm.xb[row * XBP + colg0]) + facc[0][mt][j] + f2b_0;
            x[1][mt][j] = b2f(sm.xb[row * XBP + colg1]) + facc[1][mt][j] + f2b_1;
        }
    __syncthreads();
    reg_ln(x, sm.c.ln.red, sm.c.ln.stat, sm.xb,
           ln2g[colg0], ln2g[colg1], ln2b[colg0], ln2b[colg1],
           tid, wv, col, quad, colg0, colg1);
    __syncthreads();
    // write x1 back in place (packed)
#pragma unroll
    for (int k = 0; k < 4; ++k) {
        const int idx = tid + k * NT;
        const int row = idx >> 5, seg = idx & 31;
        *(uint4*)(gptr + row * 256 + seg * 8) = *(const uint4*)(sm.xb + row * XBP + seg * 8);
    }
}

// ---------------------------------------------------------------------------
// k_l1: layer-1 last-token path (KV MFMA in 2-hp chunks, wide sections) -> x2g
// 2048 blocks x 512. LDS ~71.7 KB (2 blk/CU). Lean live set -> no spill.
// ---------------------------------------------------------------------------
struct __align__(16) SMemL {
    u16 xb[64 * XBP];                                            // 33,792 B
    u16 kvb[4 * 64 * 66];                                        // 33,792 B
    float x1row[256];
    float o1b[256];
    float q1b[256];
    float sbuf2[256];
};

__global__ __launch_bounds__(NT, 4) void k_l1(
    const u16* __restrict__ xbg,
    const u16* __restrict__ wkvb, const u16* __restrict__ wq1b,
    const u16* __restrict__ wob1,
    const float* __restrict__ qkv_b, const float* __restrict__ aob,
    float* __restrict__ x2g) {
    __shared__ SMemL sm;
    const int n = blockIdx.x;
    const int tid = threadIdx.x;
    const int lane = tid & 63, wv = tid >> 6;
    const int col = lane & 15, quad = lane >> 4;

    const float* qkv_b1 = qkv_b + 3 * EE_;
    const float* aob1p = aob + EE_;

    // load x1: global (packed) -> LDS (pitched); x1row fp32 from row 63
    const u16* src = xbg + (size_t)n * 64 * 256;
#pragma unroll
    for (int k = 0; k < 4; ++k) {
        const int idx = tid + k * NT;
        const int row = idx >> 5, seg = idx & 31;
        *(uint4*)(sm.xb + row * XBP + seg * 8) = *(const uint4*)(src + row * 256 + seg * 8);
    }
    if (tid < 256) sm.x1row[tid] = b2f(src[63 * 256 + tid]);
    __syncthreads();

#pragma unroll 1
    for (int chunk = 0; chunk < 2; ++chunk) {
        {   // KV MFMA for 2 hp (4 heads): wave = (hpc, hf, mtkh)
            const int hpc = wv & 1, hf = (wv >> 1) & 1, mtkh = (wv >> 2) & 1;
            const int hpg = chunk * 2 + hpc;
            f4_t kacc[2][4];
#pragma unroll
            for (int a = 0; a < 2; ++a)
#pragma unroll
                for (int b = 0; b < 4; ++b) kacc[a][b] = (f4_t){0.f, 0.f, 0.f, 0.f};
#pragma unroll 2
            for (int ks = 0; ks < 8; ++ks) {
                bf8_t ax[2];
#pragma unroll
                for (int m2 = 0; m2 < 2; ++m2)
                    ax[m2] = *(const bf8_t*)(sm.xb + ((mtkh * 2 + m2) * 16 + col) * XBP + ks * 32 + quad * 8);
#pragma unroll
                for (int nt = 0; nt < 4; ++nt) {
                    const int wr = hf * EE_ + hpg * 64 + nt * 16 + col;
                    const bf8_t bw = *(const bf8_t*)(wkvb + wr * EE_ + ks * 32 + quad * 8);
#pragma unroll
                    for (int m2 = 0; m2 < 2; ++m2) kacc[m2][nt] = MFMA_B16(ax[m2], bw, kacc[m2][nt]);
                }
            }
            u16* dst = sm.kvb + (hpc * 2 + hf) * 4224;
#pragma unroll
            for (int m2 = 0; m2 < 2; ++m2)
#pragma unroll
                for (int nt = 0; nt < 4; ++nt) {
                    const int cc = nt * 16 + col;
                    const float bs = qkv_b1[(hf + 1) * EE_ + hpg * 64 + cc];
                    const u32 w01 = pk_bf16(kacc[m2][nt][0] + bs, kacc[m2][nt][1] + bs);
                    const u32 w23 = pk_bf16(kacc[m2][nt][2] + bs, kacc[m2][nt][3] + bs);
                    u16* dd = dst + ((mtkh * 2 + m2) * 16 + quad * 4) * 66 + cc;
                    dd[0] = (u16)w01; dd[66] = (u16)(w01 >> 16);
                    dd[132] = (u16)w23; dd[198] = (u16)(w23 >> 16);
                }
        }
        if (chunk == 0 && tid < 256) {   // q1 for all 8 heads, one pass
            const u16* wq = wq1b + tid * EE_;
            float s = 0.f;
#pragma unroll 8
            for (int k2 = 0; k2 < 128; ++k2) {
                const u32 u = *(const u32*)(wq + k2 * 2);
                s += sm.x1row[2 * k2] * b2f_lo(u) + sm.x1row[2 * k2 + 1] * b2f_hi(u);
            }
            sm.q1b[tid] = s + qkv_b1[tid];
        }
        __syncthreads();
        if (tid < 256) {   // scores + softmax: 4 heads x 64 j (4 waves)
            const int hc = tid >> 6, jj = tid & 63;
            const int hpc = hc >> 1, hh = hc & 1;
            const u16* kr = sm.kvb + (hpc * 2) * 4224 + jj * 66 + hh * 32;
            const float* qv = sm.q1b + (chunk * 4 + hc) * 32;
            float s = 0.f;
#pragma unroll
            for (int d = 0; d < 32; ++d) s += qv[d] * b2f(kr[d]);
            s *= SCALE_;
            const float m = wmax(s);
            const float e = __expf(s - m);
            const float su = wsum(e);
            sm.sbuf2[hc * 64 + jj] = e / su;
        }
        __syncthreads();
        if (tid < 128) {   // o1: 4 heads x 32 d
            const int hc = tid >> 5, d = tid & 31;
            const int hpc = hc >> 1, hh = hc & 1;
            const u16* vr = sm.kvb + (hpc * 2 + 1) * 4224 + hh * 32 + d;
            float acc = 0.f;
            for (int j = 0; j < 64; ++j)
                acc += sm.sbuf2[hc * 64 + j] * b2f(vr[j * 66]);
            sm.o1b[(chunk * 4 + hc) * 32 + d] = acc;
        }
        __syncthreads();
    }

    // x2 = x1[63] + o1 @ Wo1^T + b  -> global
    if (tid < 256) {
        const u16* wr = wob1 + tid * EE_;
        float s = 0.f;
#pragma unroll 8
        for (int k2 = 0; k2 < 128; ++k2) {
            const u32 u = *(const u32*)(wr + k2 * 2);
            s += sm.o1b[2 * k2] * b2f_lo(u) + sm.o1b[2 * k2 + 1] * b2f_hi(u);
        }
        x2g[n * EE_ + tid] = sm.x1row[tid] + s + aob1p[tid];
    }
}

// ---------------------------------------------------------------------------
// Tail kernel: batched LN1'->FFN1'->FFN2'->LN2'->head for token 63 of all
// windows. grid = 512 blocks x 4 windows, block = 256.
// ---------------------------------------------------------------------------
__global__ __launch_bounds__(256) void k_tail(
    const float* __restrict__ x2g, const u16* __restrict__ w1b1,
    const float* __restrict__ f1b1, const u16* __restrict__ w2b1,
    const float* __restrict__ f2b1, const float* __restrict__ g1,
    const float* __restrict__ b1, const float* __restrict__ g2,
    const float* __restrict__ b2, const float* __restrict__ hw,
    const float* __restrict__ hbb, float* __restrict__ out) {
    __shared__ float xa[4 * 260];
    __shared__ float hid[4 * 1024];
    const int tid = threadIdx.x, lane = tid & 63, w = tid >> 6;
    const int n0 = blockIdx.x * 4;
    {   // LN1': one wave per window
        const float* src = x2g + (size_t)(n0 + w) * EE_;
        const float v0 = src[lane], v1 = src[lane + 64], v2 = src[lane + 128], v3 = src[lane + 192];
        const float m = wsum(v0 + v1 + v2 + v3) * 0.00390625f;
        const float d0 = v0 - m, d1 = v1 - m, d2 = v2 - m, d3 = v3 - m;
        const float var = wsum(d0 * d0 + d1 * d1 + d2 * d2 + d3 * d3) * 0.00390625f;
        const float rs = rsqrtf(var + 1e-5f);
        xa[w * 260 + lane] = d0 * rs * g1[lane] + b1[lane];
        xa[w * 260 + lane + 64] = d1 * rs * g1[lane + 64] + b1[lane + 64];
        xa[w * 260 + lane + 128] = d2 * rs * g1[lane + 128] + b1[lane + 128];
        xa[w * 260 + lane + 192] = d3 * rs * g1[lane + 192] + b1[lane + 192];
    }
    __syncthreads();
#pragma unroll 1
    for (int r = 0; r < 4; ++r) {   // FFN1
        const int f = r * 256 + tid;
        const u16* wrow = w1b1 + f * EE_;
        float a0 = 0.f, a1 = 0.f, a2 = 0.f, a3 = 0.f;
#pragma unroll 4
        for (int k2 = 0; k2 < 128; ++k2) {
            const u32 u = *(const u32*)(wrow + k2 * 2);
            const float lo = b2f_lo(u), hi = b2f_hi(u);
            const float2 h0 = *(const float2*)(xa + 0 * 260 + k2 * 2);
            const float2 h1 = *(const float2*)(xa + 1 * 260 + k2 * 2);
            const float2 h2 = *(const float2*)(xa + 2 * 260 + k2 * 2);
            const float2 h3 = *(const float2*)(xa + 3 * 260 + k2 * 2);
            a0 += h0.x * lo + h0.y * hi;
            a1 += h1.x * lo + h1.y * hi;
            a2 += h2.x * lo + h2.y * hi;
            a3 += h3.x * lo + h3.y * hi;
        }
        const float bv = f1b1[f];
        hid[0 * 1024 + f] = silu_f(a0 + bv);
        hid[1 * 1024 + f] = silu_f(a1 + bv);
        hid[2 * 1024 + f] = silu_f(a2 + bv);
        hid[3 * 1024 + f] = silu_f(a3 + bv);
    }
    __syncthreads();
    {   // FFN2
        const u16* wrow = w2b1 + tid * FF_;
        float a0 = 0.f, a1 = 0.f, a2 = 0.f, a3 = 0.f;
#pragma unroll 4
        for (int k2 = 0; k2 < 512; ++k2) {
            const u32 u = *(const u32*)(wrow + k2 * 2);
            const float lo = b2f_lo(u), hi = b2f_hi(u);
            const float2 h0 = *(const float2*)(hid + 0 * 1024 + k2 * 2);
            const float2 h1 = *(const float2*)(hid + 1 * 1024 + k2 * 2);
            const float2 h2 = *(const float2*)(hid + 2 * 1024 + k2 * 2);
            const float2 h3 = *(const float2*)(hid + 3 * 1024 + k2 * 2);
            a0 += h0.x * lo + h0.y * hi;
            a1 += h1.x * lo + h1.y * hi;
            a2 += h2.x * lo + h2.y * hi;
            a3 += h3.x * lo + h3.y * hi;
        }
        const float bv = f2b1[tid];
        const float r0 = xa[0 * 260 + tid] + a0 + bv;
        const float r1 = xa[1 * 260 + tid] + a1 + bv;
        const float r2 = xa[2 * 260 + tid] + a2 + bv;
        const float r3 = xa[3 * 260 + tid] + a3 + bv;
        __syncthreads();
        xa[0 * 260 + tid] = r0;
        xa[1 * 260 + tid] = r1;
        xa[2 * 260 + tid] = r2;
        xa[3 * 260 + tid] = r3;
    }
    __syncthreads();
    {   // LN2'
        float* row = xa + w * 260;
        const float v0 = row[lane], v1 = row[lane + 64], v2 = row[lane + 128], v3 = row[lane + 192];
        const float m = wsum(v0 + v1 + v2 + v3) * 0.00390625f;
        const float d0 = v0 - m, d1 = v1 - m, d2 = v2 - m, d3 = v3 - m;
        const float var = wsum(d0 * d0 + d1 * d1 + d2 * d2 + d3 * d3) * 0.00390625f;
        const float rs = rsqrtf(var + 1e-5f);
        __syncthreads();
        row[lane] = d0 * rs * g2[lane] + b2[lane];
        row[lane + 64] = d1 * rs * g2[lane + 64] + b2[lane + 64];
        row[lane + 128] = d2 * rs * g2[lane + 128] + b2[lane + 128];
        row[lane + 192] = d3 * rs * g2[lane + 192] + b2[lane + 192];
    }
    __syncthreads();
    if (tid < 4 * OUT_) {   // head
        const int win = tid / OUT_, o = tid % OUT_;
        const float* wr = hw + o * EE_;
        const float* xr = xa + win * 260;
        float s = 0.f;
#pragma unroll 8
        for (int c4 = 0; c4 < 64; ++c4)
            s += dot4(*(const float4*)(xr + c4 * 4), *(const float4*)(wr + c4 * 4));
        out[(n0 + win) * OUT_ + o] = s + hbb[o];
    }
}

// ---------------------------------------------------------------------------
extern "C" void kernel_launch(void* const* d_in, const int* in_sizes, int n_in,
                              void* d_out, int out_size, void* d_ws, size_t ws_size,
                              hipStream_t stream) {
    (void)in_sizes; (void)n_in; (void)out_size; (void)ws_size;
    const float* inputs = (const float*)d_in[0];
    const float* embed_w = (const float*)d_in[1];
    const float* embed_b = (const float*)d_in[2];
    const float* qkv_w = (const float*)d_in[3];
    const float* qkv_b = (const float*)d_in[4];
    const float* attn_out_w = (const float*)d_in[5];
    const float* attn_out_b = (const float*)d_in[6];
    const float* ln1_g = (const float*)d_in[7];
    const float* ln1_b = (const float*)d_in[8];
    const float* ffn1_w = (const float*)d_in[9];
    const float* ffn1_b = (const float*)d_in[10];
    const float* ffn2_w = (const float*)d_in[11];
    const float* ffn2_b = (const float*)d_in[12];
    const float* ln2_g = (const float*)d_in[13];
    const float* ln2_b = (const float*)d_in[14];
    const float* head_w = (const float*)d_in[15];
    const float* head_b = (const float*)d_in[16];
    float* out = (float*)d_out;

    char* wsb = (char*)d_ws;
    size_t off = 0;
    auto alloc = [&](size_t bytes) { char* pp = wsb + off; off += (bytes + 511) & ~511ull; return pp; };
    float* emb   = (float*)alloc((size_t)NWIN * EE_ * 4);           // 2 MB
    u16*   qkvp  = (u16*)alloc((size_t)BB_ * TPAD * 768 * 2);       // 3.34 MB
    u16*   xbg   = (u16*)alloc((size_t)NWIN * 64 * 256 * 2);        // 67 MB (x, then x1 in place)
    float* x2g   = (float*)alloc((size_t)NWIN * EE_ * 4);           // 2 MB
    u16*   w1b   = (u16*)alloc(FF_ * EE_ * 2);
    u16*   w2b   = (u16*)alloc(EE_ * FF_ * 2);
    u16*   wob   = (u16*)alloc(EE_ * EE_ * 2);
    u16*   wkvb  = (u16*)alloc(2 * EE_ * EE_ * 2);
    u16*   w1b1  = (u16*)alloc(FF_ * EE_ * 2);
    u16*   w2b1  = (u16*)alloc(EE_ * FF_ * 2);
    u16*   wob1  = (u16*)alloc(EE_ * EE_ * 2);
    u16*   wq1b  = (u16*)alloc(EE_ * EE_ * 2);
    u16*   wq0b  = (u16*)alloc(3 * EE_ * EE_ * 2);

    CvtArgs ca;
    ca.s[0] = ffn1_w;                            ca.d[0] = w1b;  ca.n[0] = FF_ * EE_;
    ca.s[1] = ffn2_w;                            ca.d[1] = w2b;  ca.n[1] = EE_ * FF_;
    ca.s[2] = attn_out_w;                        ca.d[2] = wob;  ca.n[2] = EE_ * EE_;
    ca.s[3] = qkv_w + 3 * EE_ * EE_ + EE_ * EE_; ca.d[3] = wkvb; ca.n[3] = 2 * EE_ * EE_;
    ca.s[4] = ffn1_w + FF_ * EE_;                ca.d[4] = w1b1; ca.n[4] = FF_ * EE_;
    ca.s[5] = ffn2_w + EE_ * FF_;                ca.d[5] = w2b1; ca.n[5] = EE_ * FF_;
    ca.s[6] = attn_out_w + EE_ * EE_;            ca.d[6] = wob1; ca.n[6] = EE_ * EE_;
    ca.s[7] = qkv_w + 3 * EE_ * EE_;             ca.d[7] = wq1b; ca.n[7] = EE_ * EE_;
    ca.s[8] = qkv_w;                             ca.d[8] = wq0b; ca.n[8] = 3 * EE_ * EE_;

    k_pre<<<2824, 256, 0, stream>>>(inputs, embed_w, embed_b, qkv_b, ca, emb, qkvp);
    k_qkv0m<<<NWIN / 16, 512, 0, stream>>>(emb, wq0b, qkv_b, qkvp);
    k_attn<<<NWIN, NT, 0, stream>>>(emb, qkvp, wob, attn_out_b, ln1_g, ln1_b, xbg);
    k_ffn<<<NWIN, NT, 0, stream>>>(xbg, w1b, w2b, ffn1_b, ffn2_b, ln2_g, ln2_b);
    k_l1<<<NWIN, NT, 0, stream>>>(xbg, wkvb, wq1b, wob1, qkv_b, attn_out_b, x2g);
    k_tail<<<NWIN / 4, 256, 0, stream>>>(x2g, w1b1, ffn1_b + FF_, w2b1, ffn2_b + EE_,
                                         ln1_g + EE_, ln1_b + EE_, ln2_g + EE_, ln2_b + EE_,
                                         head_w, head_b, out);
}

// Round 11
// 800.068 us; speedup vs baseline: 1.0391x; 1.0391x over previous
//
#include <hip/hip_runtime.h>
#include <hip/hip_bf16.h>

// Problem constants
#define BB_ 2
#define SS_ 1024
#define FIN_ 64
#define EE_ 256
#define FF_ 1024
#define NH_ 8
#define HD_ 32
#define OUT_ 10
#define NWIN (BB_ * SS_)
#define NT 512
#define SCALE_ 0.17677669529663687f  // 1/sqrt(32)
#define XBP 264                      // bf16 A-operand pitch (halfwords)
#define TPAD 1088                    // padded token rows per batch (64 pad + 1024)

typedef unsigned short u16;
typedef unsigned int u32;
typedef __attribute__((ext_vector_type(8))) short bf8_t;   // 8 x bf16 (4 VGPRs)
typedef __attribute__((ext_vector_type(4))) float f4_t;    // MFMA C/D
#define MFMA_B16(a, b, c) __builtin_amdgcn_mfma_f32_16x16x32_bf16(a, b, c, 0, 0, 0)

__device__ __forceinline__ u16 bf16r(float f) {
    u32 u = __builtin_bit_cast(u32, f);
    return (u16)((u + 0x7FFFu + ((u >> 16) & 1u)) >> 16);
}
__device__ __forceinline__ u32 pk_bf16(float a, float b) {
    return (u32)bf16r(a) | ((u32)bf16r(b) << 16);
}
__device__ __forceinline__ float b2f(u16 h) {
    return __builtin_bit_cast(float, ((u32)h) << 16);
}
__device__ __forceinline__ float b2f_lo(u32 u) {
    return __builtin_bit_cast(float, u << 16);
}
__device__ __forceinline__ float b2f_hi(u32 u) {
    return __builtin_bit_cast(float, u & 0xFFFF0000u);
}

__device__ __forceinline__ float dot4(float4 a, float4 b) {
    return a.x * b.x + a.y * b.y + a.z * b.z + a.w * b.w;
}
__device__ __forceinline__ float wsum(float v) {
#pragma unroll
    for (int o = 32; o > 0; o >>= 1) v += __shfl_xor(v, o, 64);
    return v;
}
__device__ __forceinline__ float wmax(float v) {
#pragma unroll
    for (int o = 32; o > 0; o >>= 1) v = fmaxf(v, __shfl_xor(v, o, 64));
    return v;
}
__device__ __forceinline__ float silu_f(float h) { return h / (1.f + __expf(-h)); }

// ---------------------------------------------------------------------------
// k_pre: fused (a) embed GEMM  (b) fp32->bf16 weight cvt  (c) qkv bias pads
// ---------------------------------------------------------------------------
struct CvtArgs {
    const float* s[9];
    u16* d[9];
    int n[9];
};

__global__ void k_pre(const float* __restrict__ in, const float* __restrict__ embw,
                      const float* __restrict__ embb, const float* __restrict__ qkv_b,
                      CvtArgs ca, float* __restrict__ emb, u16* __restrict__ qkvp) {
    __shared__ float row[FIN_];
    const int blk = blockIdx.x;
    const int tid = threadIdx.x;
    if (blk < 2048) {            // ---- embed: one token per block
        if (tid < FIN_) row[tid] = in[blk * FIN_ + tid];
        __syncthreads();
        const float4* w4 = (const float4*)(embw + tid * FIN_);
        const float4* r4 = (const float4*)row;
        float s = 0.f;
#pragma unroll
        for (int c = 0; c < FIN_ / 4; ++c) s += dot4(w4[c], r4[c]);
        emb[blk * EE_ + tid] = s + embb[tid];
    } else if (blk < 2816) {     // ---- weight conversion (768 blocks, grid-stride)
        const int b2 = blk - 2048;
#pragma unroll 1
        for (int seg = 0; seg < 9; ++seg) {
            const float* __restrict__ src = ca.s[seg];
            u16* __restrict__ dst = ca.d[seg];
            const int nn = ca.n[seg];
            for (int i = b2 * 256 + tid; i < nn; i += 768 * 256)
                dst[i] = bf16r(src[i]);
        }
    } else {                     // ---- qkv pad rows: qkvp[bat][0..63][j] = bias[j]
        const int b3 = blk - 2816;
        for (int f = b3 * 256 + tid; f < 2 * 64 * 768; f += 8 * 256) {
            const int bat = f / 49152;
            const int rem = f - bat * 49152;
            const int r = rem / 768, cl = rem - r * 768;
            qkvp[((size_t)bat * TPAD + r) * 768 + cl] = bf16r(qkv_b[cl]);
        }
    }
}

// ---------------------------------------------------------------------------
// k_qkv0m (MFMA): qkvp[bb][t+64][j] = bf16(emb[t,:] @ qkv_w0[j,:] + b[j])
// ---------------------------------------------------------------------------
__global__ __launch_bounds__(512) void k_qkv0m(const float* __restrict__ emb,
                                               const u16* __restrict__ wq0b,
                                               const float* __restrict__ qkvb,
                                               u16* __restrict__ qkvp) {
    __shared__ u16 ab[16 * XBP];
    const int b = blockIdx.x;
    const int tid = threadIdx.x, lane = tid & 63, wv = tid >> 6;
    const int col = lane & 15, quad = lane >> 4;
    for (int idx = tid; idx < 16 * 256; idx += 512) {
        const int i = idx >> 8, e = idx & 255;
        ab[i * XBP + e] = bf16r(emb[(b * 16 + i) * EE_ + e]);
    }
    __syncthreads();
    f4_t acc[6];
#pragma unroll
    for (int nt = 0; nt < 6; ++nt) acc[nt] = (f4_t){0.f, 0.f, 0.f, 0.f};
#pragma unroll
    for (int ks = 0; ks < 8; ++ks) {
        const bf8_t ax = *(const bf8_t*)(ab + col * XBP + ks * 32 + quad * 8);
#pragma unroll
        for (int nt = 0; nt < 6; ++nt) {
            const int r = wv * 96 + nt * 16 + col;
            const bf8_t bw = *(const bf8_t*)(wq0b + r * EE_ + ks * 32 + quad * 8);
            acc[nt] = MFMA_B16(ax, bw, acc[nt]);
        }
    }
#pragma unroll
    for (int nt = 0; nt < 6; ++nt) {
        const int cc = wv * 96 + nt * 16 + col;
        const float bs = qkvb[cc];
#pragma unroll
        for (int j = 0; j < 4; ++j) {
            const int tok = b * 16 + quad * 4 + j;
            const int bb = tok >> 10;
            const size_t ti = (size_t)bb * TPAD + (tok & 1023) + 64;
            qkvp[ti * 768 + cc] = bf16r(acc[nt][j] + bs);
        }
    }
}

// ---------------------------------------------------------------------------
// Shared register-LN helper over C-frag-layout state x[ntl][mt][j].
// ---------------------------------------------------------------------------
__device__ __forceinline__ void reg_ln(float (&x)[2][4][4], float* red, float* stat,
                                       u16* xb,
                                       float gc0, float gc1, float bc0, float bc1,
                                       int tid, int wv, int col, int quad,
                                       int colg0, int colg1) {
    float ps[4][4], pq[4][4];
#pragma unroll
    for (int mt = 0; mt < 4; ++mt)
#pragma unroll
        for (int j = 0; j < 4; ++j) {
            const float v0 = x[0][mt][j], v1 = x[1][mt][j];
            ps[mt][j] = v0 + v1;
            pq[mt][j] = v0 * v0 + v1 * v1;
        }
#pragma unroll
    for (int o = 1; o < 16; o <<= 1) {
#pragma unroll
        for (int mt = 0; mt < 4; ++mt)
#pragma unroll
            for (int j = 0; j < 4; ++j) {
                ps[mt][j] += __shfl_xor(ps[mt][j], o);
                pq[mt][j] += __shfl_xor(pq[mt][j], o);
            }
    }
    if (col == 0) {
#pragma unroll
        for (int mt = 0; mt < 4; ++mt)
#pragma unroll
            for (int j = 0; j < 4; ++j) {
                const int row = mt * 16 + quad * 4 + j;
                red[row * 17 + wv * 2] = ps[mt][j];
                red[row * 17 + wv * 2 + 1] = pq[mt][j];
            }
    }
    __syncthreads();
    if (tid < 64) {
        float s = 0.f, q = 0.f;
#pragma unroll
        for (int w = 0; w < 8; ++w) {
            s += red[tid * 17 + w * 2];
            q += red[tid * 17 + w * 2 + 1];
        }
        const float m = s * 0.00390625f;
        const float var = q * 0.00390625f - m * m;
        stat[tid * 2] = m;
        stat[tid * 2 + 1] = rsqrtf(var + 1e-5f);
    }
    __syncthreads();
#pragma unroll
    for (int mt = 0; mt < 4; ++mt)
#pragma unroll
        for (int j = 0; j < 4; ++j) {
            const int row = mt * 16 + quad * 4 + j;
            const float m = stat[row * 2];
            const float rs = stat[row * 2 + 1];
            const float xn0 = (x[0][mt][j] - m) * rs * gc0 + bc0;
            const float xn1 = (x[1][mt][j] - m) * rs * gc1 + bc1;
            x[0][mt][j] = xn0;
            x[1][mt][j] = xn1;
            const u32 w = pk_bf16(xn0, xn1);
            xb[row * XBP + colg0] = (u16)w;
            xb[row * XBP + colg1] = (u16)(w >> 16);
        }
}

// ---------------------------------------------------------------------------
// k_attn: attention + deferred proj + residual + LN1 -> xbg (bf16, global)
// P has its own buffer -> 2 barriers per head-pair; next-hp gather loads are
// register-staged across barrier C (lean live set, no pacc across loop).
// ---------------------------------------------------------------------------
struct __align__(16) SMemA {
    union {
        struct { u16 qkpb[9216]; u16 vt[4608]; u16 pb[9216]; } att;  // 46,080 B
        struct { float red[64 * 17]; float stat[128]; } ln;          //  4,864 B
    } r1;
    u16 obxb[64 * XBP];   // O (attn) then xb (post-LN1)             // 33,792 B
};

__global__ __launch_bounds__(NT, 4) void k_attn(
    const float* __restrict__ emb, const u16* __restrict__ qkvp,
    const u16* __restrict__ wob, const float* __restrict__ aob,
    const float* __restrict__ ln1g, const float* __restrict__ ln1b,
    u16* __restrict__ xbg) {
    __shared__ SMemA sm;
    const int n = blockIdx.x;
    const int bb = n >> 10, p = n & 1023;
    const int tid = threadIdx.x;
    const int lane = tid & 63, wv = tid >> 6;
    const int col = lane & 15, quad = lane >> 4;
    const int colg0 = wv * 32 + col, colg1 = colg0 + 16;

    // register-staged gather for hp=0
    const int gi = tid >> 3, gdg = tid & 7;
    const u16* gbase = qkvp + ((size_t)bb * TPAD + (p + 1 + gi)) * 768 + gdg * 8;
    uint4 gq = *(const uint4*)(gbase);
    uint4 gk = *(const uint4*)(gbase + 256);
    uint4 gv = *(const uint4*)(gbase + 512);

    for (int hp = 0; hp < 4; ++hp) {
        {   // stage regs -> LDS (q,k row-major; v transposed)
            *(uint4*)(sm.r1.att.qkpb + gi * 72 + gdg * 8) = gq;
            *(uint4*)(sm.r1.att.qkpb + 4608 + gi * 72 + gdg * 8) = gk;
            union { uint4 u; u16 h[8]; } vu; vu.u = gv;
#pragma unroll
            for (int c = 0; c < 8; ++c)
                sm.r1.att.vt[(gdg * 8 + c) * 72 + gi] = vu.h[c];
        }
        __syncthreads();   // A: gather visible
        const int hh = wv >> 2, mt_ = wv & 3;
        const int r0 = mt_ * 16 + quad * 4;
        // scores MFMA + in-register softmax
        const bf8_t aq = *(const bf8_t*)(sm.r1.att.qkpb + (mt_ * 16 + col) * 72 + hh * 32 + quad * 8);
        f4_t sc[4];
#pragma unroll
        for (int nt = 0; nt < 4; ++nt) {
            const bf8_t bk = *(const bf8_t*)(sm.r1.att.qkpb + 4608 + (nt * 16 + col) * 72 + hh * 32 + quad * 8);
            f4_t z = {0.f, 0.f, 0.f, 0.f};
            sc[nt] = MFMA_B16(aq, bk, z);
        }
#pragma unroll
        for (int j = 0; j < 4; ++j) {
            float s0 = sc[0][j] * SCALE_, s1 = sc[1][j] * SCALE_;
            float s2v = sc[2][j] * SCALE_, s3 = sc[3][j] * SCALE_;
            float m = fmaxf(fmaxf(s0, s1), fmaxf(s2v, s3));
            m = fmaxf(m, __shfl_xor(m, 1)); m = fmaxf(m, __shfl_xor(m, 2));
            m = fmaxf(m, __shfl_xor(m, 4)); m = fmaxf(m, __shfl_xor(m, 8));
            const float e0 = __expf(s0 - m), e1 = __expf(s1 - m);
            const float e2 = __expf(s2v - m), e3 = __expf(s3 - m);
            float s = e0 + e1 + e2 + e3;
            s += __shfl_xor(s, 1); s += __shfl_xor(s, 2);
            s += __shfl_xor(s, 4); s += __shfl_xor(s, 8);
            const float inv = 1.f / s;
            sc[0][j] = e0 * inv; sc[1][j] = e1 * inv;
            sc[2][j] = e2 * inv; sc[3][j] = e3 * inv;
        }
        // write P to its own buffer (own-wave rows only -> no barrier needed)
        u16* pbh = sm.r1.att.pb + hh * 4608;
#pragma unroll
        for (int nt = 0; nt < 4; ++nt) {
            const u32 w01 = pk_bf16(sc[nt][0], sc[nt][1]);
            const u32 w23 = pk_bf16(sc[nt][2], sc[nt][3]);
            u16* pp = pbh + r0 * 72 + nt * 16 + col;
            pp[0] = (u16)w01; pp[72] = (u16)(w01 >> 16);
            pp[144] = (u16)w23; pp[216] = (u16)(w23 >> 16);
        }
        // PV (same-wave P rows; vt stable)
        f4_t ov[2];
        ov[0] = (f4_t){0.f, 0.f, 0.f, 0.f}; ov[1] = (f4_t){0.f, 0.f, 0.f, 0.f};
#pragma unroll
        for (int ks = 0; ks < 2; ++ks) {
            const bf8_t ap = *(const bf8_t*)(pbh + (mt_ * 16 + col) * 72 + ks * 32 + quad * 8);
#pragma unroll
            for (int ntl = 0; ntl < 2; ++ntl) {
                const bf8_t bv = *(const bf8_t*)(sm.r1.att.vt +
                                                 (hh * 32 + ntl * 16 + col) * 72 + ks * 32 + quad * 8);
                ov[ntl] = MFMA_B16(ap, bv, ov[ntl]);
            }
        }
        // issue next hp's gather loads before barrier C (fly across proj of O)
        if (hp < 3) {
            const u16* gsrc = gbase + (hp + 1) * 64;
            gq = *(const uint4*)(gsrc);
            gk = *(const uint4*)(gsrc + 256);
            gv = *(const uint4*)(gsrc + 512);
        }
        // O -> full-width ob
#pragma unroll
        for (int ntl = 0; ntl < 2; ++ntl) {
            const u32 w01 = pk_bf16(ov[ntl][0], ov[ntl][1]);
            const u32 w23 = pk_bf16(ov[ntl][2], ov[ntl][3]);
            u16* oo = sm.obxb + r0 * XBP + (hp * 2 + hh) * 32 + ntl * 16 + col;
            oo[0] = (u16)w01; oo[XBP] = (u16)(w01 >> 16);
            oo[2 * XBP] = (u16)w23; oo[3 * XBP] = (u16)(w23 >> 16);
        }
        __syncthreads();   // C: q/k/vt reads done before next stage overwrites
    }

    // single proj GEMM: pacc = O @ Wo^T  (K = 256)
    f4_t pacc[2][4];
#pragma unroll
    for (int a = 0; a < 2; ++a)
#pragma unroll
        for (int m = 0; m < 4; ++m) pacc[a][m] = (f4_t){0.f, 0.f, 0.f, 0.f};
#pragma unroll 2
    for (int ks = 0; ks < 8; ++ks) {
        bf8_t ao[4];
#pragma unroll
        for (int mt = 0; mt < 4; ++mt)
            ao[mt] = *(const bf8_t*)(sm.obxb + (mt * 16 + col) * XBP + ks * 32 + quad * 8);
#pragma unroll
        for (int ntl = 0; ntl < 2; ++ntl) {
            const bf8_t bw = *(const bf8_t*)(wob + ((wv * 2 + ntl) * 16 + col) * EE_ +
                                             ks * 32 + quad * 8);
#pragma unroll
            for (int mt = 0; mt < 4; ++mt) pacc[ntl][mt] = MFMA_B16(ao[mt], bw, pacc[ntl][mt]);
        }
    }

    // combine x0 + attn + bias, LN1 -> xb in LDS
    const float aob_0 = aob[colg0], aob_1 = aob[colg1];
    float x[2][4][4];
#pragma unroll
    for (int mt = 0; mt < 4; ++mt)
#pragma unroll
        for (int j = 0; j < 4; ++j) {
            const int row = mt * 16 + quad * 4 + j;
            const int t = p - 63 + row;
            const size_t base = (size_t)((bb << 10) + t) * EE_;
            const float e0 = (t >= 0) ? emb[base + colg0] : 0.f;
            const float e1 = (t >= 0) ? emb[base + colg1] : 0.f;
            x[0][mt][j] = e0 + aob_0 + pacc[0][mt][j];
            x[1][mt][j] = e1 + aob_1 + pacc[1][mt][j];
        }
    __syncthreads();   // proj reads of ob done
    reg_ln(x, sm.r1.ln.red, sm.r1.ln.stat, sm.obxb,
           ln1g[colg0], ln1g[colg1], ln1b[colg0], ln1b[colg1],
           tid, wv, col, quad, colg0, colg1);
    __syncthreads();
    // coalesced copy-out: LDS xb (pitch 264) -> global (packed 256/row)
    u16* dst = xbg + (size_t)n * 64 * 256;
#pragma unroll
    for (int k = 0; k < 4; ++k) {
        const int idx = tid + k * NT;
        const int row = idx >> 5, seg = idx & 31;
        *(uint4*)(dst + row * 256 + seg * 8) = *(const uint4*)(sm.obxb + row * XBP + seg * 8);
    }
}

// ---------------------------------------------------------------------------
// k_mlp: FFN (double-buffered hb, merged phases; ffn2 first for overlap) +
// LN2 + layer-1 (2-hp chunks, wide sections) -> x2g. LDS ~72.7 KB (2 blk/CU).
// ---------------------------------------------------------------------------
struct __align__(16) SMemB {
    u16 xb[64 * XBP];                                            // 33,792 B
    union {
        u16 hb2[2][64 * 136];                                    // 34,816 B
        u16 kvb[4 * 64 * 66];                                    // 33,792 B
        struct { float red[64 * 17]; float stat[128]; } ln;      //  4,864 B
    } c;
    float x1row[256];
    float o1b[256];
    float q1b[256];
    float sbuf2[256];
};

__global__ __launch_bounds__(NT, 4) void k_mlp(
    const u16* __restrict__ xbg,
    const u16* __restrict__ w1b, const u16* __restrict__ w2b,
    const u16* __restrict__ wkvb, const u16* __restrict__ wq1b,
    const u16* __restrict__ wob1,
    const float* __restrict__ qkv_b, const float* __restrict__ aob,
    const float* __restrict__ f1b, const float* __restrict__ f2b,
    const float* __restrict__ ln2g, const float* __restrict__ ln2b,
    float* __restrict__ x2g) {
    __shared__ SMemB sm;
    const int n = blockIdx.x;
    const int tid = threadIdx.x;
    const int lane = tid & 63, wv = tid >> 6;
    const int col = lane & 15, quad = lane >> 4;
    const int colg0 = wv * 32 + col, colg1 = colg0 + 16;

    const float* qkv_b1 = qkv_b + 3 * EE_;
    const float* aob1p = aob + EE_;

    // load xb: global (packed) -> LDS (pitched)
    const u16* src = xbg + (size_t)n * 64 * 256;
#pragma unroll
    for (int k = 0; k < 4; ++k) {
        const int idx = tid + k * NT;
        const int row = idx >> 5, seg = idx & 31;
        *(uint4*)(sm.xb + row * XBP + seg * 8) = *(const uint4*)(src + row * 256 + seg * 8);
    }
    __syncthreads();

    // ---- FFN: double-buffered hb, merged phases (ffn2 of c before ffn1 of c+1)
    f4_t facc[2][4];
#pragma unroll
    for (int a = 0; a < 2; ++a)
#pragma unroll
        for (int m = 0; m < 4; ++m) facc[a][m] = (f4_t){0.f, 0.f, 0.f, 0.f};

    auto ffn1_step = [&](int c) {
        f4_t hacc[4];
#pragma unroll
        for (int m = 0; m < 4; ++m) hacc[m] = (f4_t){0.f, 0.f, 0.f, 0.f};
        const int f = c * 128 + wv * 16 + col;
#pragma unroll 2
        for (int ks = 0; ks < 8; ++ks) {
            const bf8_t bw = *(const bf8_t*)(w1b + f * EE_ + ks * 32 + quad * 8);
#pragma unroll
            for (int mt = 0; mt < 4; ++mt) {
                const bf8_t axr = *(const bf8_t*)(sm.xb + (mt * 16 + col) * XBP + ks * 32 + quad * 8);
                hacc[mt] = MFMA_B16(axr, bw, hacc[mt]);
            }
        }
        const float bv = f1b[f];
        const int lc = wv * 16 + col;
        u16* hbc = sm.c.hb2[c & 1];
#pragma unroll
        for (int mt = 0; mt < 4; ++mt) {
            const u32 w01 = pk_bf16(silu_f(hacc[mt][0] + bv), silu_f(hacc[mt][1] + bv));
            const u32 w23 = pk_bf16(silu_f(hacc[mt][2] + bv), silu_f(hacc[mt][3] + bv));
            u16* hh2 = hbc + (mt * 16 + quad * 4) * 136 + lc;
            hh2[0] = (u16)w01; hh2[136] = (u16)(w01 >> 16);
            hh2[272] = (u16)w23; hh2[408] = (u16)(w23 >> 16);
        }
    };
    auto ffn2_step = [&](int c) {
        const u16* hbc = sm.c.hb2[c & 1];
#pragma unroll 2
        for (int ks = 0; ks < 4; ++ks) {
            bf8_t ah[4];
#pragma unroll
            for (int mt = 0; mt < 4; ++mt)
                ah[mt] = *(const bf8_t*)(hbc + (mt * 16 + col) * 136 + ks * 32 + quad * 8);
#pragma unroll
            for (int ntl = 0; ntl < 2; ++ntl) {
                const int e = (wv * 2 + ntl) * 16 + col;
                const bf8_t bw = *(const bf8_t*)(w2b + e * FF_ + c * 128 + ks * 32 + quad * 8);
#pragma unroll
                for (int mt = 0; mt < 4; ++mt) facc[ntl][mt] = MFMA_B16(ah[mt], bw, facc[ntl][mt]);
            }
        }
    };

    ffn1_step(0);
    __syncthreads();
#pragma unroll 1
    for (int c = 0; c < 8; ++c) {
        ffn2_step(c);                  // reads  hb2[c&1] (ready at barrier)
        if (c < 7) ffn1_step(c + 1);   // writes hb2[(c+1)&1]
        __syncthreads();
    }

    // reconstruct x from bf16 xb, add FFN2 + bias, LN2 -> x1
    const float f2b_0 = f2b[colg0], f2b_1 = f2b[colg1];
    float x[2][4][4];
#pragma unroll
    for (int mt = 0; mt < 4; ++mt)
#pragma unroll
        for (int j = 0; j < 4; ++j) {
            const int row = mt * 16 + quad * 4 + j;
            x[0][mt][j] = b2f(sm.xb[row * XBP + colg0]) + facc[0][mt][j] + f2b_0;
            x[1][mt][j] = b2f(sm.xb[row * XBP + colg1]) + facc[1][mt][j] + f2b_1;
        }
    __syncthreads();   // xb/hb reads done before reg_ln overwrites
    reg_ln(x, sm.c.ln.red, sm.c.ln.stat, sm.xb,
           ln2g[colg0], ln2g[colg1], ln2b[colg0], ln2b[colg1],
           tid, wv, col, quad, colg0, colg1);
    if (quad == 3) {   // row 63 holder: mt=3, quad=3, j=3
        sm.x1row[colg0] = x[0][3][3];
        sm.x1row[colg1] = x[1][3][3];
    }
    __syncthreads();

    // =================== Layer 1: 2 head-pairs per chunk ===================
#pragma unroll 1
    for (int chunk = 0; chunk < 2; ++chunk) {
        {   // KV MFMA for 2 hp (4 heads): wave = (hpc, hf, mtkh)
            const int hpc = wv & 1, hf = (wv >> 1) & 1, mtkh = (wv >> 2) & 1;
            const int hpg = chunk * 2 + hpc;
            f4_t kacc[2][4];
#pragma unroll
            for (int a = 0; a < 2; ++a)
#pragma unroll
                for (int b = 0; b < 4; ++b) kacc[a][b] = (f4_t){0.f, 0.f, 0.f, 0.f};
#pragma unroll 2
            for (int ks = 0; ks < 8; ++ks) {
                bf8_t ax[2];
#pragma unroll
                for (int m2 = 0; m2 < 2; ++m2)
                    ax[m2] = *(const bf8_t*)(sm.xb + ((mtkh * 2 + m2) * 16 + col) * XBP + ks * 32 + quad * 8);
#pragma unroll
                for (int nt = 0; nt < 4; ++nt) {
                    const int wr = hf * EE_ + hpg * 64 + nt * 16 + col;
                    const bf8_t bw = *(const bf8_t*)(wkvb + wr * EE_ + ks * 32 + quad * 8);
#pragma unroll
                    for (int m2 = 0; m2 < 2; ++m2) kacc[m2][nt] = MFMA_B16(ax[m2], bw, kacc[m2][nt]);
                }
            }
            u16* dst = sm.c.kvb + (hpc * 2 + hf) * 4224;
#pragma unroll
            for (int m2 = 0; m2 < 2; ++m2)
#pragma unroll
                for (int nt = 0; nt < 4; ++nt) {
                    const int cc = nt * 16 + col;
                    const float bs = qkv_b1[(hf + 1) * EE_ + hpg * 64 + cc];
                    const u32 w01 = pk_bf16(kacc[m2][nt][0] + bs, kacc[m2][nt][1] + bs);
                    const u32 w23 = pk_bf16(kacc[m2][nt][2] + bs, kacc[m2][nt][3] + bs);
                    u16* dd = dst + ((mtkh * 2 + m2) * 16 + quad * 4) * 66 + cc;
                    dd[0] = (u16)w01; dd[66] = (u16)(w01 >> 16);
                    dd[132] = (u16)w23; dd[198] = (u16)(w23 >> 16);
                }
        }
        if (chunk == 0 && tid < 256) {   // q1 for all 8 heads, one pass
            const u16* wq = wq1b + tid * EE_;
            float s = 0.f;
#pragma unroll 8
            for (int k2 = 0; k2 < 128; ++k2) {
                const u32 u = *(const u32*)(wq + k2 * 2);
                s += sm.x1row[2 * k2] * b2f_lo(u) + sm.x1row[2 * k2 + 1] * b2f_hi(u);
            }
            sm.q1b[tid] = s + qkv_b1[tid];
        }
        __syncthreads();
        if (tid < 256) {   // scores + softmax: 4 heads x 64 j (4 waves)
            const int hc = tid >> 6, jj = tid & 63;
            const int hpc = hc >> 1, hh = hc & 1;
            const u16* kr = sm.c.kvb + (hpc * 2) * 4224 + jj * 66 + hh * 32;
            const float* qv = sm.q1b + (chunk * 4 + hc) * 32;
            float s = 0.f;
#pragma unroll
            for (int d = 0; d < 32; ++d) s += qv[d] * b2f(kr[d]);
            s *= SCALE_;
            const float m = wmax(s);
            const float e = __expf(s - m);
            const float su = wsum(e);
            sm.sbuf2[hc * 64 + jj] = e / su;
        }
        __syncthreads();
        if (tid < 128) {   // o1: 4 heads x 32 d
            const int hc = tid >> 5, d = tid & 31;
            const int hpc = hc >> 1, hh = hc & 1;
            const u16* vr = sm.c.kvb + (hpc * 2 + 1) * 4224 + hh * 32 + d;
            float acc = 0.f;
            for (int j = 0; j < 64; ++j)
                acc += sm.sbuf2[hc * 64 + j] * b2f(vr[j * 66]);
            sm.o1b[(chunk * 4 + hc) * 32 + d] = acc;
        }
        __syncthreads();
    }

    // x2 = x1[63] + o1 @ Wo1^T + b  -> global
    if (tid < 256) {
        const u16* wr = wob1 + tid * EE_;
        float s = 0.f;
#pragma unroll 8
        for (int k2 = 0; k2 < 128; ++k2) {
            const u32 u = *(const u32*)(wr + k2 * 2);
            s += sm.o1b[2 * k2] * b2f_lo(u) + sm.o1b[2 * k2 + 1] * b2f_hi(u);
        }
        x2g[n * EE_ + tid] = sm.x1row[tid] + s + aob1p[tid];
    }
}

// ---------------------------------------------------------------------------
// Tail kernel: batched LN1'->FFN1'->FFN2'->LN2'->head for token 63 of all
// windows. grid = 512 blocks x 4 windows, block = 256.
// ---------------------------------------------------------------------------
__global__ __launch_bounds__(256) void k_tail(
    const float* __restrict__ x2g, const u16* __restrict__ w1b1,
    const float* __restrict__ f1b1, const u16* __restrict__ w2b1,
    const float* __restrict__ f2b1, const float* __restrict__ g1,
    const float* __restrict__ b1, const float* __restrict__ g2,
    const float* __restrict__ b2, const float* __restrict__ hw,
    const float* __restrict__ hbb, float* __restrict__ out) {
    __shared__ float xa[4 * 260];
    __shared__ float hid[4 * 1024];
    const int tid = threadIdx.x, lane = tid & 63, w = tid >> 6;
    const int n0 = blockIdx.x * 4;
    {   // LN1': one wave per window
        const float* src = x2g + (size_t)(n0 + w) * EE_;
        const float v0 = src[lane], v1 = src[lane + 64], v2 = src[lane + 128], v3 = src[lane + 192];
        const float m = wsum(v0 + v1 + v2 + v3) * 0.00390625f;
        const float d0 = v0 - m, d1 = v1 - m, d2 = v2 - m, d3 = v3 - m;
        const float var = wsum(d0 * d0 + d1 * d1 + d2 * d2 + d3 * d3) * 0.00390625f;
        const float rs = rsqrtf(var + 1e-5f);
        xa[w * 260 + lane] = d0 * rs * g1[lane] + b1[lane];
        xa[w * 260 + lane + 64] = d1 * rs * g1[lane + 64] + b1[lane + 64];
        xa[w * 260 + lane + 128] = d2 * rs * g1[lane + 128] + b1[lane + 128];
        xa[w * 260 + lane + 192] = d3 * rs * g1[lane + 192] + b1[lane + 192];
    }
    __syncthreads();
#pragma unroll 1
    for (int r = 0; r < 4; ++r) {   // FFN1
        const int f = r * 256 + tid;
        const u16* wrow = w1b1 + f * EE_;
        float a0 = 0.f, a1 = 0.f, a2 = 0.f, a3 = 0.f;
#pragma unroll 4
        for (int k2 = 0; k2 < 128; ++k2) {
            const u32 u = *(const u32*)(wrow + k2 * 2);
            const float lo = b2f_lo(u), hi = b2f_hi(u);
            const float2 h0 = *(const float2*)(xa + 0 * 260 + k2 * 2);
            const float2 h1 = *(const float2*)(xa + 1 * 260 + k2 * 2);
            const float2 h2 = *(const float2*)(xa + 2 * 260 + k2 * 2);
            const float2 h3 = *(const float2*)(xa + 3 * 260 + k2 * 2);
            a0 += h0.x * lo + h0.y * hi;
            a1 += h1.x * lo + h1.y * hi;
            a2 += h2.x * lo + h2.y * hi;
            a3 += h3.x * lo + h3.y * hi;
        }
        const float bv = f1b1[f];
        hid[0 * 1024 + f] = silu_f(a0 + bv);
        hid[1 * 1024 + f] = silu_f(a1 + bv);
        hid[2 * 1024 + f] = silu_f(a2 + bv);
        hid[3 * 1024 + f] = silu_f(a3 + bv);
    }
    __syncthreads();
    {   // FFN2
        const u16* wrow = w2b1 + tid * FF_;
        float a0 = 0.f, a1 = 0.f, a2 = 0.f, a3 = 0.f;
#pragma unroll 4
        for (int k2 = 0; k2 < 512; ++k2) {
            const u32 u = *(const u32*)(wrow + k2 * 2);
            const float lo = b2f_lo(u), hi = b2f_hi(u);
            const float2 h0 = *(const float2*)(hid + 0 * 1024 + k2 * 2);
            const float2 h1 = *(const float2*)(hid + 1 * 1024 + k2 * 2);
            const float2 h2 = *(const float2*)(hid + 2 * 1024 + k2 * 2);
            const float2 h3 = *(const float2*)(hid + 3 * 1024 + k2 * 2);
            a0 += h0.x * lo + h0.y * hi;
            a1 += h1.x * lo + h1.y * hi;
            a2 += h2.x * lo + h2.y * hi;
            a3 += h3.x * lo + h3.y * hi;
        }
        const float bv = f2b1[tid];
        const float r0 = xa[0 * 260 + tid] + a0 + bv;
        const float r1 = xa[1 * 260 + tid] + a1 + bv;
        const float r2 = xa[2 * 260 + tid] + a2 + bv;
        const float r3 = xa[3 * 260 + tid] + a3 + bv;
        __syncthreads();
        xa[0 * 260 + tid] = r0;
        xa[1 * 260 + tid] = r1;
        xa[2 * 260 + tid] = r2;
        xa[3 * 260 + tid] = r3;
    }
    __syncthreads();
    {   // LN2'
        float* row = xa + w * 260;
        const float v0 = row[lane], v1 = row[lane + 64], v2 = row[lane + 128], v3 = row[lane + 192];
        const float m = wsum(v0 + v1 + v2 + v3) * 0.00390625f;
        const float d0 = v0 - m, d1 = v1 - m, d2 = v2 - m, d3 = v3 - m;
        const float var = wsum(d0 * d0 + d1 * d1 + d2 * d2 + d3 * d3) * 0.00390625f;
        const float rs = rsqrtf(var + 1e-5f);
        __syncthreads();
        row[lane] = d0 * rs * g2[lane] + b2[lane];
        row[lane + 64] = d1 * rs * g2[lane + 64] + b2[lane + 64];
        row[lane + 128] = d2 * rs * g2[lane + 128] + b2[lane + 128];
        row[lane + 192] = d3 * rs * g2[lane + 192] + b2[lane + 192];
    }
    __syncthreads();
    if (tid < 4 * OUT_) {   // head
        const int win = tid / OUT_, o = tid % OUT_;
        const float* wr = hw + o * EE_;
        const float* xr = xa + win * 260;
        float s = 0.f;
#pragma unroll 8
        for (int c4 = 0; c4 < 64; ++c4)
            s += dot4(*(const float4*)(xr + c4 * 4), *(const float4*)(wr + c4 * 4));
        out[(n0 + win) * OUT_ + o] = s + hbb[o];
    }
}

// ---------------------------------------------------------------------------
extern "C" void kernel_launch(void* const* d_in, const int* in_sizes, int n_in,
                              void* d_out, int out_size, void* d_ws, size_t ws_size,
                              hipStream_t stream) {
    (void)in_sizes; (void)n_in; (void)out_size; (void)ws_size;
    const float* inputs = (const float*)d_in[0];
    const float* embed_w = (const float*)d_in[1];
    const float* embed_b = (const float*)d_in[2];
    const float* qkv_w = (const float*)d_in[3];
    const float* qkv_b = (const float*)d_in[4];
    const float* attn_out_w = (const float*)d_in[5];
    const float* attn_out_b = (const float*)d_in[6];
    const float* ln1_g = (const float*)d_in[7];
    const float* ln1_b = (const float*)d_in[8];
    const float* ffn1_w = (const float*)d_in[9];
    const float* ffn1_b = (const float*)d_in[10];
    const float* ffn2_w = (const float*)d_in[11];
    const float* ffn2_b = (const float*)d_in[12];
    const float* ln2_g = (const float*)d_in[13];
    const float* ln2_b = (const float*)d_in[14];
    const float* head_w = (const float*)d_in[15];
    const float* head_b = (const float*)d_in[16];
    float* out = (float*)d_out;

    char* wsb = (char*)d_ws;
    size_t off = 0;
    auto alloc = [&](size_t bytes) { char* pp = wsb + off; off += (bytes + 511) & ~511ull; return pp; };
    float* emb   = (float*)alloc((size_t)NWIN * EE_ * 4);           // 2 MB
    u16*   qkvp  = (u16*)alloc((size_t)BB_ * TPAD * 768 * 2);       // 3.34 MB
    u16*   xbg   = (u16*)alloc((size_t)NWIN * 64 * 256 * 2);        // 67 MB
    float* x2g   = (float*)alloc((size_t)NWIN * EE_ * 4);           // 2 MB
    u16*   w1b   = (u16*)alloc(FF_ * EE_ * 2);
    u16*   w2b   = (u16*)alloc(EE_ * FF_ * 2);
    u16*   wob   = (u16*)alloc(EE_ * EE_ * 2);
    u16*   wkvb  = (u16*)alloc(2 * EE_ * EE_ * 2);
    u16*   w1b1  = (u16*)alloc(FF_ * EE_ * 2);
    u16*   w2b1  = (u16*)alloc(EE_ * FF_ * 2);
    u16*   wob1  = (u16*)alloc(EE_ * EE_ * 2);
    u16*   wq1b  = (u16*)alloc(EE_ * EE_ * 2);
    u16*   wq0b  = (u16*)alloc(3 * EE_ * EE_ * 2);

    CvtArgs ca;
    ca.s[0] = ffn1_w;                            ca.d[0] = w1b;  ca.n[0] = FF_ * EE_;
    ca.s[1] = ffn2_w;                            ca.d[1] = w2b;  ca.n[1] = EE_ * FF_;
    ca.s[2] = attn_out_w;                        ca.d[2] = wob;  ca.n[2] = EE_ * EE_;
    ca.s[3] = qkv_w + 3 * EE_ * EE_ + EE_ * EE_; ca.d[3] = wkvb; ca.n[3] = 2 * EE_ * EE_;
    ca.s[4] = ffn1_w + FF_ * EE_;                ca.d[4] = w1b1; ca.n[4] = FF_ * EE_;
    ca.s[5] = ffn2_w + EE_ * FF_;                ca.d[5] = w2b1; ca.n[5] = EE_ * FF_;
    ca.s[6] = attn_out_w + EE_ * EE_;            ca.d[6] = wob1; ca.n[6] = EE_ * EE_;
    ca.s[7] = qkv_w + 3 * EE_ * EE_;             ca.d[7] = wq1b; ca.n[7] = EE_ * EE_;
    ca.s[8] = qkv_w;                             ca.d[8] = wq0b; ca.n[8] = 3 * EE_ * EE_;

    k_pre<<<2824, 256, 0, stream>>>(inputs, embed_w, embed_b, qkv_b, ca, emb, qkvp);
    k_qkv0m<<<NWIN / 16, 512, 0, stream>>>(emb, wq0b, qkv_b, qkvp);
    k_attn<<<NWIN, NT, 0, stream>>>(emb, qkvp, wob, attn_out_b, ln1_g, ln1_b, xbg);
    k_mlp<<<NWIN, NT, 0, stream>>>(xbg, w1b, w2b, wkvb, wq1b, wob1,
                                   qkv_b, attn_out_b, ffn1_b, ffn2_b,
                                   ln2_g, ln2_b, x2g);
    k_tail<<<NWIN / 4, 256, 0, stream>>>(x2g, w1b1, ffn1_b + FF_, w2b1, ffn2_b + EE_,
                                         ln1_g + EE_, ln1_b + EE_, ln2_g + EE_, ln2_b + EE_,
                                         head_w, head_b, out);
}

// Round 12
// 794.232 us; speedup vs baseline: 1.0468x; 1.0073x over previous
//
#include <hip/hip_runtime.h>
#include <hip/hip_bf16.h>

// Problem constants
#define BB_ 2
#define SS_ 1024
#define FIN_ 64
#define EE_ 256
#define FF_ 1024
#define NH_ 8
#define HD_ 32
#define OUT_ 10
#define NWIN (BB_ * SS_)
#define NT 512
#define SCALE_ 0.17677669529663687f  // 1/sqrt(32)
#define XBP 264                      // bf16 A-operand pitch (halfwords)
#define TPAD 1088                    // padded token rows per batch (64 pad + 1024)

typedef unsigned short u16;
typedef unsigned int u32;
typedef __attribute__((ext_vector_type(8))) short bf8_t;   // 8 x bf16 (4 VGPRs)
typedef __attribute__((ext_vector_type(4))) float f4_t;    // MFMA C/D
#define MFMA_B16(a, b, c) __builtin_amdgcn_mfma_f32_16x16x32_bf16(a, b, c, 0, 0, 0)

__device__ __forceinline__ u16 bf16r(float f) {
    u32 u = __builtin_bit_cast(u32, f);
    return (u16)((u + 0x7FFFu + ((u >> 16) & 1u)) >> 16);
}
__device__ __forceinline__ u32 pk_bf16(float a, float b) {
    return (u32)bf16r(a) | ((u32)bf16r(b) << 16);
}
__device__ __forceinline__ float b2f(u16 h) {
    return __builtin_bit_cast(float, ((u32)h) << 16);
}
__device__ __forceinline__ float b2f_lo(u32 u) {
    return __builtin_bit_cast(float, u << 16);
}
__device__ __forceinline__ float b2f_hi(u32 u) {
    return __builtin_bit_cast(float, u & 0xFFFF0000u);
}

__device__ __forceinline__ float dot4(float4 a, float4 b) {
    return a.x * b.x + a.y * b.y + a.z * b.z + a.w * b.w;
}
__device__ __forceinline__ float wsum(float v) {
#pragma unroll
    for (int o = 32; o > 0; o >>= 1) v += __shfl_xor(v, o, 64);
    return v;
}
__device__ __forceinline__ float wmax(float v) {
#pragma unroll
    for (int o = 32; o > 0; o >>= 1) v = fmaxf(v, __shfl_xor(v, o, 64));
    return v;
}
__device__ __forceinline__ float silu_f(float h) { return h / (1.f + __expf(-h)); }

// ---------------------------------------------------------------------------
// k_pre: fused (a) embed GEMM  (b) fp32->bf16 weight cvt  (c) qkv bias pads
// ---------------------------------------------------------------------------
struct CvtArgs {
    const float* s[9];
    u16* d[9];
    int n[9];
};

__global__ void k_pre(const float* __restrict__ in, const float* __restrict__ embw,
                      const float* __restrict__ embb, const float* __restrict__ qkv_b,
                      CvtArgs ca, float* __restrict__ emb, u16* __restrict__ qkvp) {
    __shared__ float row[FIN_];
    const int blk = blockIdx.x;
    const int tid = threadIdx.x;
    if (blk < 2048) {            // ---- embed: one token per block
        if (tid < FIN_) row[tid] = in[blk * FIN_ + tid];
        __syncthreads();
        const float4* w4 = (const float4*)(embw + tid * FIN_);
        const float4* r4 = (const float4*)row;
        float s = 0.f;
#pragma unroll
        for (int c = 0; c < FIN_ / 4; ++c) s += dot4(w4[c], r4[c]);
        emb[blk * EE_ + tid] = s + embb[tid];
    } else if (blk < 2816) {     // ---- weight conversion (768 blocks, grid-stride)
        const int b2 = blk - 2048;
#pragma unroll 1
        for (int seg = 0; seg < 9; ++seg) {
            const float* __restrict__ src = ca.s[seg];
            u16* __restrict__ dst = ca.d[seg];
            const int nn = ca.n[seg];
            for (int i = b2 * 256 + tid; i < nn; i += 768 * 256)
                dst[i] = bf16r(src[i]);
        }
    } else {                     // ---- qkv pad rows: qkvp[bat][0..63][j] = bias[j]
        const int b3 = blk - 2816;
        for (int f = b3 * 256 + tid; f < 2 * 64 * 768; f += 8 * 256) {
            const int bat = f / 49152;
            const int rem = f - bat * 49152;
            const int r = rem / 768, cl = rem - r * 768;
            qkvp[((size_t)bat * TPAD + r) * 768 + cl] = bf16r(qkv_b[cl]);
        }
    }
}

// ---------------------------------------------------------------------------
// k_qkv0m (MFMA): qkvp[bb][t+64][j] = bf16(emb[t,:] @ qkv_w0[j,:] + b[j])
// ---------------------------------------------------------------------------
__global__ __launch_bounds__(512) void k_qkv0m(const float* __restrict__ emb,
                                               const u16* __restrict__ wq0b,
                                               const float* __restrict__ qkvb,
                                               u16* __restrict__ qkvp) {
    __shared__ u16 ab[16 * XBP];
    const int b = blockIdx.x;
    const int tid = threadIdx.x, lane = tid & 63, wv = tid >> 6;
    const int col = lane & 15, quad = lane >> 4;
    for (int idx = tid; idx < 16 * 256; idx += 512) {
        const int i = idx >> 8, e = idx & 255;
        ab[i * XBP + e] = bf16r(emb[(b * 16 + i) * EE_ + e]);
    }
    __syncthreads();
    f4_t acc[6];
#pragma unroll
    for (int nt = 0; nt < 6; ++nt) acc[nt] = (f4_t){0.f, 0.f, 0.f, 0.f};
#pragma unroll
    for (int ks = 0; ks < 8; ++ks) {
        const bf8_t ax = *(const bf8_t*)(ab + col * XBP + ks * 32 + quad * 8);
#pragma unroll
        for (int nt = 0; nt < 6; ++nt) {
            const int r = wv * 96 + nt * 16 + col;
            const bf8_t bw = *(const bf8_t*)(wq0b + r * EE_ + ks * 32 + quad * 8);
            acc[nt] = MFMA_B16(ax, bw, acc[nt]);
        }
    }
#pragma unroll
    for (int nt = 0; nt < 6; ++nt) {
        const int cc = wv * 96 + nt * 16 + col;
        const float bs = qkvb[cc];
#pragma unroll
        for (int j = 0; j < 4; ++j) {
            const int tok = b * 16 + quad * 4 + j;
            const int bb = tok >> 10;
            const size_t ti = (size_t)bb * TPAD + (tok & 1023) + 64;
            qkvp[ti * 768 + cc] = bf16r(acc[nt][j] + bs);
        }
    }
}

// ---------------------------------------------------------------------------
// Shared register-LN helper over C-frag-layout state x[ntl][mt][j].
// ---------------------------------------------------------------------------
__device__ __forceinline__ void reg_ln(float (&x)[2][4][4], float* red, float* stat,
                                       u16* xb,
                                       float gc0, float gc1, float bc0, float bc1,
                                       int tid, int wv, int col, int quad,
                                       int colg0, int colg1) {
    float ps[4][4], pq[4][4];
#pragma unroll
    for (int mt = 0; mt < 4; ++mt)
#pragma unroll
        for (int j = 0; j < 4; ++j) {
            const float v0 = x[0][mt][j], v1 = x[1][mt][j];
            ps[mt][j] = v0 + v1;
            pq[mt][j] = v0 * v0 + v1 * v1;
        }
#pragma unroll
    for (int o = 1; o < 16; o <<= 1) {
#pragma unroll
        for (int mt = 0; mt < 4; ++mt)
#pragma unroll
            for (int j = 0; j < 4; ++j) {
                ps[mt][j] += __shfl_xor(ps[mt][j], o);
                pq[mt][j] += __shfl_xor(pq[mt][j], o);
            }
    }
    if (col == 0) {
#pragma unroll
        for (int mt = 0; mt < 4; ++mt)
#pragma unroll
            for (int j = 0; j < 4; ++j) {
                const int row = mt * 16 + quad * 4 + j;
                red[row * 17 + wv * 2] = ps[mt][j];
                red[row * 17 + wv * 2 + 1] = pq[mt][j];
            }
    }
    __syncthreads();
    if (tid < 64) {
        float s = 0.f, q = 0.f;
#pragma unroll
        for (int w = 0; w < 8; ++w) {
            s += red[tid * 17 + w * 2];
            q += red[tid * 17 + w * 2 + 1];
        }
        const float m = s * 0.00390625f;
        const float var = q * 0.00390625f - m * m;
        stat[tid * 2] = m;
        stat[tid * 2 + 1] = rsqrtf(var + 1e-5f);
    }
    __syncthreads();
#pragma unroll
    for (int mt = 0; mt < 4; ++mt)
#pragma unroll
        for (int j = 0; j < 4; ++j) {
            const int row = mt * 16 + quad * 4 + j;
            const float m = stat[row * 2];
            const float rs = stat[row * 2 + 1];
            const float xn0 = (x[0][mt][j] - m) * rs * gc0 + bc0;
            const float xn1 = (x[1][mt][j] - m) * rs * gc1 + bc1;
            x[0][mt][j] = xn0;
            x[1][mt][j] = xn1;
            const u32 w = pk_bf16(xn0, xn1);
            xb[row * XBP + colg0] = (u16)w;
            xb[row * XBP + colg1] = (u16)(w >> 16);
        }
}

// ---------------------------------------------------------------------------
// k_attn: attention + deferred proj + residual + LN1 -> xbg (bf16, global)
// P has its own buffer -> 2 barriers per head-pair; next-hp gather loads are
// register-staged across barrier C (lean live set, no pacc across loop).
// ---------------------------------------------------------------------------
struct __align__(16) SMemA {
    union {
        struct { u16 qkpb[9216]; u16 vt[4608]; u16 pb[9216]; } att;  // 46,080 B
        struct { float red[64 * 17]; float stat[128]; } ln;          //  4,864 B
    } r1;
    u16 obxb[64 * XBP];   // O (attn) then xb (post-LN1)             // 33,792 B
};

__global__ __launch_bounds__(NT, 4) void k_attn(
    const float* __restrict__ emb, const u16* __restrict__ qkvp,
    const u16* __restrict__ wob, const float* __restrict__ aob,
    const float* __restrict__ ln1g, const float* __restrict__ ln1b,
    u16* __restrict__ xbg) {
    __shared__ SMemA sm;
    const int n = blockIdx.x;
    const int bb = n >> 10, p = n & 1023;
    const int tid = threadIdx.x;
    const int lane = tid & 63, wv = tid >> 6;
    const int col = lane & 15, quad = lane >> 4;
    const int colg0 = wv * 32 + col, colg1 = colg0 + 16;

    // register-staged gather for hp=0
    const int gi = tid >> 3, gdg = tid & 7;
    const u16* gbase = qkvp + ((size_t)bb * TPAD + (p + 1 + gi)) * 768 + gdg * 8;
    uint4 gq = *(const uint4*)(gbase);
    uint4 gk = *(const uint4*)(gbase + 256);
    uint4 gv = *(const uint4*)(gbase + 512);

    for (int hp = 0; hp < 4; ++hp) {
        {   // stage regs -> LDS (q,k row-major; v transposed)
            *(uint4*)(sm.r1.att.qkpb + gi * 72 + gdg * 8) = gq;
            *(uint4*)(sm.r1.att.qkpb + 4608 + gi * 72 + gdg * 8) = gk;
            union { uint4 u; u16 h[8]; } vu; vu.u = gv;
#pragma unroll
            for (int c = 0; c < 8; ++c)
                sm.r1.att.vt[(gdg * 8 + c) * 72 + gi] = vu.h[c];
        }
        __syncthreads();   // A: gather visible
        const int hh = wv >> 2, mt_ = wv & 3;
        const int r0 = mt_ * 16 + quad * 4;
        // scores MFMA + in-register softmax
        const bf8_t aq = *(const bf8_t*)(sm.r1.att.qkpb + (mt_ * 16 + col) * 72 + hh * 32 + quad * 8);
        f4_t sc[4];
#pragma unroll
        for (int nt = 0; nt < 4; ++nt) {
            const bf8_t bk = *(const bf8_t*)(sm.r1.att.qkpb + 4608 + (nt * 16 + col) * 72 + hh * 32 + quad * 8);
            f4_t z = {0.f, 0.f, 0.f, 0.f};
            sc[nt] = MFMA_B16(aq, bk, z);
        }
#pragma unroll
        for (int j = 0; j < 4; ++j) {
            float s0 = sc[0][j] * SCALE_, s1 = sc[1][j] * SCALE_;
            float s2v = sc[2][j] * SCALE_, s3 = sc[3][j] * SCALE_;
            float m = fmaxf(fmaxf(s0, s1), fmaxf(s2v, s3));
            m = fmaxf(m, __shfl_xor(m, 1)); m = fmaxf(m, __shfl_xor(m, 2));
            m = fmaxf(m, __shfl_xor(m, 4)); m = fmaxf(m, __shfl_xor(m, 8));
            const float e0 = __expf(s0 - m), e1 = __expf(s1 - m);
            const float e2 = __expf(s2v - m), e3 = __expf(s3 - m);
            float s = e0 + e1 + e2 + e3;
            s += __shfl_xor(s, 1); s += __shfl_xor(s, 2);
            s += __shfl_xor(s, 4); s += __shfl_xor(s, 8);
            const float inv = 1.f / s;
            sc[0][j] = e0 * inv; sc[1][j] = e1 * inv;
            sc[2][j] = e2 * inv; sc[3][j] = e3 * inv;
        }
        // write P to its own buffer (own-wave rows only -> no barrier needed)
        u16* pbh = sm.r1.att.pb + hh * 4608;
#pragma unroll
        for (int nt = 0; nt < 4; ++nt) {
            const u32 w01 = pk_bf16(sc[nt][0], sc[nt][1]);
            const u32 w23 = pk_bf16(sc[nt][2], sc[nt][3]);
            u16* pp = pbh + r0 * 72 + nt * 16 + col;
            pp[0] = (u16)w01; pp[72] = (u16)(w01 >> 16);
            pp[144] = (u16)w23; pp[216] = (u16)(w23 >> 16);
        }
        // PV (same-wave P rows; vt stable)
        f4_t ov[2];
        ov[0] = (f4_t){0.f, 0.f, 0.f, 0.f}; ov[1] = (f4_t){0.f, 0.f, 0.f, 0.f};
#pragma unroll
        for (int ks = 0; ks < 2; ++ks) {
            const bf8_t ap = *(const bf8_t*)(pbh + (mt_ * 16 + col) * 72 + ks * 32 + quad * 8);
#pragma unroll
            for (int ntl = 0; ntl < 2; ++ntl) {
                const bf8_t bv = *(const bf8_t*)(sm.r1.att.vt +
                                                 (hh * 32 + ntl * 16 + col) * 72 + ks * 32 + quad * 8);
                ov[ntl] = MFMA_B16(ap, bv, ov[ntl]);
            }
        }
        // issue next hp's gather loads before barrier C (fly across O-write)
        if (hp < 3) {
            const u16* gsrc = gbase + (hp + 1) * 64;
            gq = *(const uint4*)(gsrc);
            gk = *(const uint4*)(gsrc + 256);
            gv = *(const uint4*)(gsrc + 512);
        }
        // O -> full-width ob
#pragma unroll
        for (int ntl = 0; ntl < 2; ++ntl) {
            const u32 w01 = pk_bf16(ov[ntl][0], ov[ntl][1]);
            const u32 w23 = pk_bf16(ov[ntl][2], ov[ntl][3]);
            u16* oo = sm.obxb + r0 * XBP + (hp * 2 + hh) * 32 + ntl * 16 + col;
            oo[0] = (u16)w01; oo[XBP] = (u16)(w01 >> 16);
            oo[2 * XBP] = (u16)w23; oo[3 * XBP] = (u16)(w23 >> 16);
        }
        __syncthreads();   // C: q/k/vt reads done before next stage overwrites
    }

    // single proj GEMM: pacc = O @ Wo^T  (K = 256)
    f4_t pacc[2][4];
#pragma unroll
    for (int a = 0; a < 2; ++a)
#pragma unroll
        for (int m = 0; m < 4; ++m) pacc[a][m] = (f4_t){0.f, 0.f, 0.f, 0.f};
#pragma unroll 2
    for (int ks = 0; ks < 8; ++ks) {
        bf8_t ao[4];
#pragma unroll
        for (int mt = 0; mt < 4; ++mt)
            ao[mt] = *(const bf8_t*)(sm.obxb + (mt * 16 + col) * XBP + ks * 32 + quad * 8);
#pragma unroll
        for (int ntl = 0; ntl < 2; ++ntl) {
            const bf8_t bw = *(const bf8_t*)(wob + ((wv * 2 + ntl) * 16 + col) * EE_ +
                                             ks * 32 + quad * 8);
#pragma unroll
            for (int mt = 0; mt < 4; ++mt) pacc[ntl][mt] = MFMA_B16(ao[mt], bw, pacc[ntl][mt]);
        }
    }

    // combine x0 + attn + bias, LN1 -> xb in LDS
    const float aob_0 = aob[colg0], aob_1 = aob[colg1];
    float x[2][4][4];
#pragma unroll
    for (int mt = 0; mt < 4; ++mt)
#pragma unroll
        for (int j = 0; j < 4; ++j) {
            const int row = mt * 16 + quad * 4 + j;
            const int t = p - 63 + row;
            const size_t base = (size_t)((bb << 10) + t) * EE_;
            const float e0 = (t >= 0) ? emb[base + colg0] : 0.f;
            const float e1 = (t >= 0) ? emb[base + colg1] : 0.f;
            x[0][mt][j] = e0 + aob_0 + pacc[0][mt][j];
            x[1][mt][j] = e1 + aob_1 + pacc[1][mt][j];
        }
    __syncthreads();   // proj reads of ob done
    reg_ln(x, sm.r1.ln.red, sm.r1.ln.stat, sm.obxb,
           ln1g[colg0], ln1g[colg1], ln1b[colg0], ln1b[colg1],
           tid, wv, col, quad, colg0, colg1);
    __syncthreads();
    // coalesced copy-out: LDS xb (pitch 264) -> global (packed 256/row)
    u16* dst = xbg + (size_t)n * 64 * 256;
#pragma unroll
    for (int k = 0; k < 4; ++k) {
        const int idx = tid + k * NT;
        const int row = idx >> 5, seg = idx & 31;
        *(uint4*)(dst + row * 256 + seg * 8) = *(const uint4*)(sm.obxb + row * XBP + seg * 8);
    }
}

// ---------------------------------------------------------------------------
// k_mlp: FFN (double-buffered hb, merged phases, ffn1-first = R9 order) +
// LN2 + layer-1 (2-hp chunks, wide sections) -> x2g. LDS ~72.7 KB (2 blk/CU).
// ---------------------------------------------------------------------------
struct __align__(16) SMemB {
    u16 xb[64 * XBP];                                            // 33,792 B
    union {
        u16 hb2[2][64 * 136];                                    // 34,816 B
        u16 kvb[4 * 64 * 66];                                    // 33,792 B
        struct { float red[64 * 17]; float stat[128]; } ln;      //  4,864 B
    } c;
    float x1row[256];
    float o1b[256];
    float q1b[256];
    float sbuf2[256];
};

__global__ __launch_bounds__(NT, 4) void k_mlp(
    const u16* __restrict__ xbg,
    const u16* __restrict__ w1b, const u16* __restrict__ w2b,
    const u16* __restrict__ wkvb, const u16* __restrict__ wq1b,
    const u16* __restrict__ wob1,
    const float* __restrict__ qkv_b, const float* __restrict__ aob,
    const float* __restrict__ f1b, const float* __restrict__ f2b,
    const float* __restrict__ ln2g, const float* __restrict__ ln2b,
    float* __restrict__ x2g) {
    __shared__ SMemB sm;
    const int n = blockIdx.x;
    const int tid = threadIdx.x;
    const int lane = tid & 63, wv = tid >> 6;
    const int col = lane & 15, quad = lane >> 4;
    const int colg0 = wv * 32 + col, colg1 = colg0 + 16;

    const float* qkv_b1 = qkv_b + 3 * EE_;
    const float* aob1p = aob + EE_;

    // load xb: global (packed) -> LDS (pitched)
    const u16* src = xbg + (size_t)n * 64 * 256;
#pragma unroll
    for (int k = 0; k < 4; ++k) {
        const int idx = tid + k * NT;
        const int row = idx >> 5, seg = idx & 31;
        *(uint4*)(sm.xb + row * XBP + seg * 8) = *(const uint4*)(src + row * 256 + seg * 8);
    }
    __syncthreads();

    // ---- FFN: double-buffered hb, merged phases (ffn1 of c+1 first — R9)
    f4_t facc[2][4];
#pragma unroll
    for (int a = 0; a < 2; ++a)
#pragma unroll
        for (int m = 0; m < 4; ++m) facc[a][m] = (f4_t){0.f, 0.f, 0.f, 0.f};

    auto ffn1_step = [&](int c) {
        f4_t hacc[4];
#pragma unroll
        for (int m = 0; m < 4; ++m) hacc[m] = (f4_t){0.f, 0.f, 0.f, 0.f};
        const int f = c * 128 + wv * 16 + col;
#pragma unroll 2
        for (int ks = 0; ks < 8; ++ks) {
            const bf8_t bw = *(const bf8_t*)(w1b + f * EE_ + ks * 32 + quad * 8);
#pragma unroll
            for (int mt = 0; mt < 4; ++mt) {
                const bf8_t axr = *(const bf8_t*)(sm.xb + (mt * 16 + col) * XBP + ks * 32 + quad * 8);
                hacc[mt] = MFMA_B16(axr, bw, hacc[mt]);
            }
        }
        const float bv = f1b[f];
        const int lc = wv * 16 + col;
        u16* hbc = sm.c.hb2[c & 1];
#pragma unroll
        for (int mt = 0; mt < 4; ++mt) {
            const u32 w01 = pk_bf16(silu_f(hacc[mt][0] + bv), silu_f(hacc[mt][1] + bv));
            const u32 w23 = pk_bf16(silu_f(hacc[mt][2] + bv), silu_f(hacc[mt][3] + bv));
            u16* hh2 = hbc + (mt * 16 + quad * 4) * 136 + lc;
            hh2[0] = (u16)w01; hh2[136] = (u16)(w01 >> 16);
            hh2[272] = (u16)w23; hh2[408] = (u16)(w23 >> 16);
        }
    };
    auto ffn2_step = [&](int c) {
        const u16* hbc = sm.c.hb2[c & 1];
#pragma unroll 2
        for (int ks = 0; ks < 4; ++ks) {
            bf8_t ah[4];
#pragma unroll
            for (int mt = 0; mt < 4; ++mt)
                ah[mt] = *(const bf8_t*)(hbc + (mt * 16 + col) * 136 + ks * 32 + quad * 8);
#pragma unroll
            for (int ntl = 0; ntl < 2; ++ntl) {
                const int e = (wv * 2 + ntl) * 16 + col;
                const bf8_t bw = *(const bf8_t*)(w2b + e * FF_ + c * 128 + ks * 32 + quad * 8);
#pragma unroll
                for (int mt = 0; mt < 4; ++mt) facc[ntl][mt] = MFMA_B16(ah[mt], bw, facc[ntl][mt]);
            }
        }
    };

    ffn1_step(0);
    __syncthreads();
#pragma unroll 1
    for (int c = 0; c < 8; ++c) {
        if (c < 7) ffn1_step(c + 1);   // writes hb2[(c+1)&1] (loads issued early)
        ffn2_step(c);                  // reads  hb2[c&1]
        __syncthreads();
    }

    // reconstruct x from bf16 xb, add FFN2 + bias, LN2 -> x1
    const float f2b_0 = f2b[colg0], f2b_1 = f2b[colg1];
    float x[2][4][4];
#pragma unroll
    for (int mt = 0; mt < 4; ++mt)
#pragma unroll
        for (int j = 0; j < 4; ++j) {
            const int row = mt * 16 + quad * 4 + j;
            x[0][mt][j] = b2f(sm.xb[row * XBP + colg0]) + facc[0][mt][j] + f2b_0;
            x[1][mt][j] = b2f(sm.xb[row * XBP + colg1]) + facc[1][mt][j] + f2b_1;
        }
    __syncthreads();   // xb/hb reads done before reg_ln overwrites
    reg_ln(x, sm.c.ln.red, sm.c.ln.stat, sm.xb,
           ln2g[colg0], ln2g[colg1], ln2b[colg0], ln2b[colg1],
           tid, wv, col, quad, colg0, colg1);
    if (quad == 3) {   // row 63 holder: mt=3, quad=3, j=3
        sm.x1row[colg0] = x[0][3][3];
        sm.x1row[colg1] = x[1][3][3];
    }
    __syncthreads();

    // =================== Layer 1: 2 head-pairs per chunk ===================
#pragma unroll 1
    for (int chunk = 0; chunk < 2; ++chunk) {
        {   // KV MFMA for 2 hp (4 heads): wave = (hpc, hf, mtkh)
            const int hpc = wv & 1, hf = (wv >> 1) & 1, mtkh = (wv >> 2) & 1;
            const int hpg = chunk * 2 + hpc;
            f4_t kacc[2][4];
#pragma unroll
            for (int a = 0; a < 2; ++a)
#pragma unroll
                for (int b = 0; b < 4; ++b) kacc[a][b] = (f4_t){0.f, 0.f, 0.f, 0.f};
#pragma unroll 2
            for (int ks = 0; ks < 8; ++ks) {
                bf8_t ax[2];
#pragma unroll
                for (int m2 = 0; m2 < 2; ++m2)
                    ax[m2] = *(const bf8_t*)(sm.xb + ((mtkh * 2 + m2) * 16 + col) * XBP + ks * 32 + quad * 8);
#pragma unroll
                for (int nt = 0; nt < 4; ++nt) {
                    const int wr = hf * EE_ + hpg * 64 + nt * 16 + col;
                    const bf8_t bw = *(const bf8_t*)(wkvb + wr * EE_ + ks * 32 + quad * 8);
#pragma unroll
                    for (int m2 = 0; m2 < 2; ++m2) kacc[m2][nt] = MFMA_B16(ax[m2], bw, kacc[m2][nt]);
                }
            }
            u16* dst = sm.c.kvb + (hpc * 2 + hf) * 4224;
#pragma unroll
            for (int m2 = 0; m2 < 2; ++m2)
#pragma unroll
                for (int nt = 0; nt < 4; ++nt) {
                    const int cc = nt * 16 + col;
                    const float bs = qkv_b1[(hf + 1) * EE_ + hpg * 64 + cc];
                    const u32 w01 = pk_bf16(kacc[m2][nt][0] + bs, kacc[m2][nt][1] + bs);
                    const u32 w23 = pk_bf16(kacc[m2][nt][2] + bs, kacc[m2][nt][3] + bs);
                    u16* dd = dst + ((mtkh * 2 + m2) * 16 + quad * 4) * 66 + cc;
                    dd[0] = (u16)w01; dd[66] = (u16)(w01 >> 16);
                    dd[132] = (u16)w23; dd[198] = (u16)(w23 >> 16);
                }
        }
        if (chunk == 0 && tid < 256) {   // q1 for all 8 heads, one pass
            const u16* wq = wq1b + tid * EE_;
            float s = 0.f;
#pragma unroll 8
            for (int k2 = 0; k2 < 128; ++k2) {
                const u32 u = *(const u32*)(wq + k2 * 2);
                s += sm.x1row[2 * k2] * b2f_lo(u) + sm.x1row[2 * k2 + 1] * b2f_hi(u);
            }
            sm.q1b[tid] = s + qkv_b1[tid];
        }
        __syncthreads();
        if (tid < 256) {   // scores + softmax: 4 heads x 64 j (4 waves)
            const int hc = tid >> 6, jj = tid & 63;
            const int hpc = hc >> 1, hh = hc & 1;
            const u16* kr = sm.c.kvb + (hpc * 2) * 4224 + jj * 66 + hh * 32;
            const float* qv = sm.q1b + (chunk * 4 + hc) * 32;
            float s = 0.f;
#pragma unroll
            for (int d = 0; d < 32; ++d) s += qv[d] * b2f(kr[d]);
            s *= SCALE_;
            const float m = wmax(s);
            const float e = __expf(s - m);
            const float su = wsum(e);
            sm.sbuf2[hc * 64 + jj] = e / su;
        }
        __syncthreads();
        if (tid < 128) {   // o1: 4 heads x 32 d
            const int hc = tid >> 5, d = tid & 31;
            const int hpc = hc >> 1, hh = hc & 1;
            const u16* vr = sm.c.kvb + (hpc * 2 + 1) * 4224 + hh * 32 + d;
            float acc = 0.f;
            for (int j = 0; j < 64; ++j)
                acc += sm.sbuf2[hc * 64 + j] * b2f(vr[j * 66]);
            sm.o1b[(chunk * 4 + hc) * 32 + d] = acc;
        }
        __syncthreads();
    }

    // x2 = x1[63] + o1 @ Wo1^T + b  -> global
    if (tid < 256) {
        const u16* wr = wob1 + tid * EE_;
        float s = 0.f;
#pragma unroll 8
        for (int k2 = 0; k2 < 128; ++k2) {
            const u32 u = *(const u32*)(wr + k2 * 2);
            s += sm.o1b[2 * k2] * b2f_lo(u) + sm.o1b[2 * k2 + 1] * b2f_hi(u);
        }
        x2g[n * EE_ + tid] = sm.x1row[tid] + s + aob1p[tid];
    }
}

// ---------------------------------------------------------------------------
// Tail kernel: batched LN1'->FFN1'->FFN2'->LN2'->head for token 63 of all
// windows. grid = 512 blocks x 4 windows, block = 256.
// ---------------------------------------------------------------------------
__global__ __launch_bounds__(256) void k_tail(
    const float* __restrict__ x2g, const u16* __restrict__ w1b1,
    const float* __restrict__ f1b1, const u16* __restrict__ w2b1,
    const float* __restrict__ f2b1, const float* __restrict__ g1,
    const float* __restrict__ b1, const float* __restrict__ g2,
    const float* __restrict__ b2, const float* __restrict__ hw,
    const float* __restrict__ hbb, float* __restrict__ out) {
    __shared__ float xa[4 * 260];
    __shared__ float hid[4 * 1024];
    const int tid = threadIdx.x, lane = tid & 63, w = tid >> 6;
    const int n0 = blockIdx.x * 4;
    {   // LN1': one wave per window
        const float* src = x2g + (size_t)(n0 + w) * EE_;
        const float v0 = src[lane], v1 = src[lane + 64], v2 = src[lane + 128], v3 = src[lane + 192];
        const float m = wsum(v0 + v1 + v2 + v3) * 0.00390625f;
        const float d0 = v0 - m, d1 = v1 - m, d2 = v2 - m, d3 = v3 - m;
        const float var = wsum(d0 * d0 + d1 * d1 + d2 * d2 + d3 * d3) * 0.00390625f;
        const float rs = rsqrtf(var + 1e-5f);
        xa[w * 260 + lane] = d0 * rs * g1[lane] + b1[lane];
        xa[w * 260 + lane + 64] = d1 * rs * g1[lane + 64] + b1[lane + 64];
        xa[w * 260 + lane + 128] = d2 * rs * g1[lane + 128] + b1[lane + 128];
        xa[w * 260 + lane + 192] = d3 * rs * g1[lane + 192] + b1[lane + 192];
    }
    __syncthreads();
#pragma unroll 1
    for (int r = 0; r < 4; ++r) {   // FFN1
        const int f = r * 256 + tid;
        const u16* wrow = w1b1 + f * EE_;
        float a0 = 0.f, a1 = 0.f, a2 = 0.f, a3 = 0.f;
#pragma unroll 4
        for (int k2 = 0; k2 < 128; ++k2) {
            const u32 u = *(const u32*)(wrow + k2 * 2);
            const float lo = b2f_lo(u), hi = b2f_hi(u);
            const float2 h0 = *(const float2*)(xa + 0 * 260 + k2 * 2);
            const float2 h1 = *(const float2*)(xa + 1 * 260 + k2 * 2);
            const float2 h2 = *(const float2*)(xa + 2 * 260 + k2 * 2);
            const float2 h3 = *(const float2*)(xa + 3 * 260 + k2 * 2);
            a0 += h0.x * lo + h0.y * hi;
            a1 += h1.x * lo + h1.y * hi;
            a2 += h2.x * lo + h2.y * hi;
            a3 += h3.x * lo + h3.y * hi;
        }
        const float bv = f1b1[f];
        hid[0 * 1024 + f] = silu_f(a0 + bv);
        hid[1 * 1024 + f] = silu_f(a1 + bv);
        hid[2 * 1024 + f] = silu_f(a2 + bv);
        hid[3 * 1024 + f] = silu_f(a3 + bv);
    }
    __syncthreads();
    {   // FFN2
        const u16* wrow = w2b1 + tid * FF_;
        float a0 = 0.f, a1 = 0.f, a2 = 0.f, a3 = 0.f;
#pragma unroll 4
        for (int k2 = 0; k2 < 512; ++k2) {
            const u32 u = *(const u32*)(wrow + k2 * 2);
            const float lo = b2f_lo(u), hi = b2f_hi(u);
            const float2 h0 = *(const float2*)(hid + 0 * 1024 + k2 * 2);
            const float2 h1 = *(const float2*)(hid + 1 * 1024 + k2 * 2);
            const float2 h2 = *(const float2*)(hid + 2 * 1024 + k2 * 2);
            const float2 h3 = *(const float2*)(hid + 3 * 1024 + k2 * 2);
            a0 += h0.x * lo + h0.y * hi;
            a1 += h1.x * lo + h1.y * hi;
            a2 += h2.x * lo + h2.y * hi;
            a3 += h3.x * lo + h3.y * hi;
        }
        const float bv = f2b1[tid];
        const float r0 = xa[0 * 260 + tid] + a0 + bv;
        const float r1 = xa[1 * 260 + tid] + a1 + bv;
        const float r2 = xa[2 * 260 + tid] + a2 + bv;
        const float r3 = xa[3 * 260 + tid] + a3 + bv;
        __syncthreads();
        xa[0 * 260 + tid] = r0;
        xa[1 * 260 + tid] = r1;
        xa[2 * 260 + tid] = r2;
        xa[3 * 260 + tid] = r3;
    }
    __syncthreads();
    {   // LN2'
        float* row = xa + w * 260;
        const float v0 = row[lane], v1 = row[lane + 64], v2 = row[lane + 128], v3 = row[lane + 192];
        const float m = wsum(v0 + v1 + v2 + v3) * 0.00390625f;
        const float d0 = v0 - m, d1 = v1 - m, d2 = v2 - m, d3 = v3 - m;
        const float var = wsum(d0 * d0 + d1 * d1 + d2 * d2 + d3 * d3) * 0.00390625f;
        const float rs = rsqrtf(var + 1e-5f);
        __syncthreads();
        row[lane] = d0 * rs * g2[lane] + b2[lane];
        row[lane + 64] = d1 * rs * g2[lane + 64] + b2[lane + 64];
        row[lane + 128] = d2 * rs * g2[lane + 128] + b2[lane + 128];
        row[lane + 192] = d3 * rs * g2[lane + 192] + b2[lane + 192];
    }
    __syncthreads();
    if (tid < 4 * OUT_) {   // head
        const int win = tid / OUT_, o = tid % OUT_;
        const float* wr = hw + o * EE_;
        const float* xr = xa + win * 260;
        float s = 0.f;
#pragma unroll 8
        for (int c4 = 0; c4 < 64; ++c4)
            s += dot4(*(const float4*)(xr + c4 * 4), *(const float4*)(wr + c4 * 4));
        out[(n0 + win) * OUT_ + o] = s + hbb[o];
    }
}

// ---------------------------------------------------------------------------
extern "C" void kernel_launch(void* const* d_in, const int* in_sizes, int n_in,
                              void* d_out, int out_size, void* d_ws, size_t ws_size,
                              hipStream_t stream) {
    (void)in_sizes; (void)n_in; (void)out_size; (void)ws_size;
    const float* inputs = (const float*)d_in[0];
    const float* embed_w = (const float*)d_in[1];
    const float* embed_b = (const float*)d_in[2];
    const float* qkv_w = (const float*)d_in[3];
    const float* qkv_b = (const float*)d_in[4];
    const float* attn_out_w = (const float*)d_in[5];
    const float* attn_out_b = (const float*)d_in[6];
    const float* ln1_g = (const float*)d_in[7];
    const float* ln1_b = (const float*)d_in[8];
    const float* ffn1_w = (const float*)d_in[9];
    const float* ffn1_b = (const float*)d_in[10];
    const float* ffn2_w = (const float*)d_in[11];
    const float* ffn2_b = (const float*)d_in[12];
    const float* ln2_g = (const float*)d_in[13];
    const float* ln2_b = (const float*)d_in[14];
    const float* head_w = (const float*)d_in[15];
    const float* head_b = (const float*)d_in[16];
    float* out = (float*)d_out;

    char* wsb = (char*)d_ws;
    size_t off = 0;
    auto alloc = [&](size_t bytes) { char* pp = wsb + off; off += (bytes + 511) & ~511ull; return pp; };
    float* emb   = (float*)alloc((size_t)NWIN * EE_ * 4);           // 2 MB
    u16*   qkvp  = (u16*)alloc((size_t)BB_ * TPAD * 768 * 2);       // 3.34 MB
    u16*   xbg   = (u16*)alloc((size_t)NWIN * 64 * 256 * 2);        // 67 MB
    float* x2g   = (float*)alloc((size_t)NWIN * EE_ * 4);           // 2 MB
    u16*   w1b   = (u16*)alloc(FF_ * EE_ * 2);
    u16*   w2b   = (u16*)alloc(EE_ * FF_ * 2);
    u16*   wob   = (u16*)alloc(EE_ * EE_ * 2);
    u16*   wkvb  = (u16*)alloc(2 * EE_ * EE_ * 2);
    u16*   w1b1  = (u16*)alloc(FF_ * EE_ * 2);
    u16*   w2b1  = (u16*)alloc(EE_ * FF_ * 2);
    u16*   wob1  = (u16*)alloc(EE_ * EE_ * 2);
    u16*   wq1b  = (u16*)alloc(EE_ * EE_ * 2);
    u16*   wq0b  = (u16*)alloc(3 * EE_ * EE_ * 2);

    CvtArgs ca;
    ca.s[0] = ffn1_w;                            ca.d[0] = w1b;  ca.n[0] = FF_ * EE_;
    ca.s[1] = ffn2_w;                            ca.d[1] = w2b;  ca.n[1] = EE_ * FF_;
    ca.s[2] = attn_out_w;                        ca.d[2] = wob;  ca.n[2] = EE_ * EE_;
    ca.s[3] = qkv_w + 3 * EE_ * EE_ + EE_ * EE_; ca.d[3] = wkvb; ca.n[3] = 2 * EE_ * EE_;
    ca.s[4] = ffn1_w + FF_ * EE_;                ca.d[4] = w1b1; ca.n[4] = FF_ * EE_;
    ca.s[5] = ffn2_w + EE_ * FF_;                ca.d[5] = w2b1; ca.n[5] = EE_ * FF_;
    ca.s[6] = attn_out_w + EE_ * EE_;            ca.d[6] = wob1; ca.n[6] = EE_ * EE_;
    ca.s[7] = qkv_w + 3 * EE_ * EE_;             ca.d[7] = wq1b; ca.n[7] = EE_ * EE_;
    ca.s[8] = qkv_w;                             ca.d[8] = wq0b; ca.n[8] = 3 * EE_ * EE_;

    k_pre<<<2824, 256, 0, stream>>>(inputs, embed_w, embed_b, qkv_b, ca, emb, qkvp);
    k_qkv0m<<<NWIN / 16, 512, 0, stream>>>(emb, wq0b, qkv_b, qkvp);
    k_attn<<<NWIN, NT, 0, stream>>>(emb, qkvp, wob, attn_out_b, ln1_g, ln1_b, xbg);
    k_mlp<<<NWIN, NT, 0, stream>>>(xbg, w1b, w2b, wkvb, wq1b, wob1,
                                   qkv_b, attn_out_b, ffn1_b, ffn2_b,
                                   ln2_g, ln2_b, x2g);
    k_tail<<<NWIN / 4, 256, 0, stream>>>(x2g, w1b1, ffn1_b + FF_, w2b1, ffn2_b + EE_,
                                         ln1_g + EE_, ln1_b + EE_, ln2_g + EE_, ln2_b + EE_,
                                         head_w, head_b, out);
}

// Round 13
// 785.931 us; speedup vs baseline: 1.0578x; 1.0106x over previous
//
#include <hip/hip_runtime.h>
#include <hip/hip_bf16.h>

// Problem constants
#define BB_ 2
#define SS_ 1024
#define FIN_ 64
#define EE_ 256
#define FF_ 1024
#define NH_ 8
#define HD_ 32
#define OUT_ 10
#define NWIN (BB_ * SS_)
#define NT 512
#define SCALE_ 0.17677669529663687f  // 1/sqrt(32)
#define XBP 264                      // bf16 A-operand pitch (halfwords)
#define TPAD 1088                    // padded token rows per batch (64 pad + 1024)

typedef unsigned short u16;
typedef unsigned int u32;
typedef __attribute__((ext_vector_type(8))) short bf8_t;   // 8 x bf16 (4 VGPRs)
typedef __attribute__((ext_vector_type(4))) float f4_t;    // MFMA C/D
#define MFMA_B16(a, b, c) __builtin_amdgcn_mfma_f32_16x16x32_bf16(a, b, c, 0, 0, 0)

__device__ __forceinline__ u16 bf16r(float f) {
    u32 u = __builtin_bit_cast(u32, f);
    return (u16)((u + 0x7FFFu + ((u >> 16) & 1u)) >> 16);
}
__device__ __forceinline__ u32 pk_bf16(float a, float b) {
    return (u32)bf16r(a) | ((u32)bf16r(b) << 16);
}
__device__ __forceinline__ float b2f(u16 h) {
    return __builtin_bit_cast(float, ((u32)h) << 16);
}
__device__ __forceinline__ float b2f_lo(u32 u) {
    return __builtin_bit_cast(float, u << 16);
}
__device__ __forceinline__ float b2f_hi(u32 u) {
    return __builtin_bit_cast(float, u & 0xFFFF0000u);
}

__device__ __forceinline__ float dot4(float4 a, float4 b) {
    return a.x * b.x + a.y * b.y + a.z * b.z + a.w * b.w;
}
__device__ __forceinline__ float wsum(float v) {
#pragma unroll
    for (int o = 32; o > 0; o >>= 1) v += __shfl_xor(v, o, 64);
    return v;
}
__device__ __forceinline__ float wmax(float v) {
#pragma unroll
    for (int o = 32; o > 0; o >>= 1) v = fmaxf(v, __shfl_xor(v, o, 64));
    return v;
}
__device__ __forceinline__ float silu_f(float h) { return h / (1.f + __expf(-h)); }

// ---------------------------------------------------------------------------
// k_pre: fused (a) embed GEMM  (b) fp32->bf16 weight cvt  (c) qkv bias pads
// ---------------------------------------------------------------------------
struct CvtArgs {
    const float* s[9];
    u16* d[9];
    int n[9];
};

__global__ void k_pre(const float* __restrict__ in, const float* __restrict__ embw,
                      const float* __restrict__ embb, const float* __restrict__ qkv_b,
                      CvtArgs ca, float* __restrict__ emb, u16* __restrict__ qkvp) {
    __shared__ float row[FIN_];
    const int blk = blockIdx.x;
    const int tid = threadIdx.x;
    if (blk < 2048) {            // ---- embed: one token per block
        if (tid < FIN_) row[tid] = in[blk * FIN_ + tid];
        __syncthreads();
        const float4* w4 = (const float4*)(embw + tid * FIN_);
        const float4* r4 = (const float4*)row;
        float s = 0.f;
#pragma unroll
        for (int c = 0; c < FIN_ / 4; ++c) s += dot4(w4[c], r4[c]);
        emb[blk * EE_ + tid] = s + embb[tid];
    } else if (blk < 2816) {     // ---- weight conversion (768 blocks, grid-stride)
        const int b2 = blk - 2048;
#pragma unroll 1
        for (int seg = 0; seg < 9; ++seg) {
            const float* __restrict__ src = ca.s[seg];
            u16* __restrict__ dst = ca.d[seg];
            const int nn = ca.n[seg];
            for (int i = b2 * 256 + tid; i < nn; i += 768 * 256)
                dst[i] = bf16r(src[i]);
        }
    } else {                     // ---- qkv pad rows: qkvp[bat][0..63][j] = bias[j]
        const int b3 = blk - 2816;
        for (int f = b3 * 256 + tid; f < 2 * 64 * 768; f += 8 * 256) {
            const int bat = f / 49152;
            const int rem = f - bat * 49152;
            const int r = rem / 768, cl = rem - r * 768;
            qkvp[((size_t)bat * TPAD + r) * 768 + cl] = bf16r(qkv_b[cl]);
        }
    }
}

// ---------------------------------------------------------------------------
// k_qkv0m (MFMA): qkvp[bb][t+64][j] = bf16(emb[t,:] @ qkv_w0[j,:] + b[j])
// ---------------------------------------------------------------------------
__global__ __launch_bounds__(512) void k_qkv0m(const float* __restrict__ emb,
                                               const u16* __restrict__ wq0b,
                                               const float* __restrict__ qkvb,
                                               u16* __restrict__ qkvp) {
    __shared__ u16 ab[16 * XBP];
    const int b = blockIdx.x;
    const int tid = threadIdx.x, lane = tid & 63, wv = tid >> 6;
    const int col = lane & 15, quad = lane >> 4;
    for (int idx = tid; idx < 16 * 256; idx += 512) {
        const int i = idx >> 8, e = idx & 255;
        ab[i * XBP + e] = bf16r(emb[(b * 16 + i) * EE_ + e]);
    }
    __syncthreads();
    f4_t acc[6];
#pragma unroll
    for (int nt = 0; nt < 6; ++nt) acc[nt] = (f4_t){0.f, 0.f, 0.f, 0.f};
#pragma unroll
    for (int ks = 0; ks < 8; ++ks) {
        const bf8_t ax = *(const bf8_t*)(ab + col * XBP + ks * 32 + quad * 8);
#pragma unroll
        for (int nt = 0; nt < 6; ++nt) {
            const int r = wv * 96 + nt * 16 + col;
            const bf8_t bw = *(const bf8_t*)(wq0b + r * EE_ + ks * 32 + quad * 8);
            acc[nt] = MFMA_B16(ax, bw, acc[nt]);
        }
    }
#pragma unroll
    for (int nt = 0; nt < 6; ++nt) {
        const int cc = wv * 96 + nt * 16 + col;
        const float bs = qkvb[cc];
#pragma unroll
        for (int j = 0; j < 4; ++j) {
            const int tok = b * 16 + quad * 4 + j;
            const int bb = tok >> 10;
            const size_t ti = (size_t)bb * TPAD + (tok & 1023) + 64;
            qkvp[ti * 768 + cc] = bf16r(acc[nt][j] + bs);
        }
    }
}

// ---------------------------------------------------------------------------
// Shared register-LN helper over C-frag-layout state x[ntl][mt][j].
// Restructured (R13): ps/pq reduced per-mt (8 live) instead of all-32 live —
// keeps peak arch-register demand under the 64-reg budget, eliminating the
// scratch spill of x around the LN. Numerics identical to previous version.
// ---------------------------------------------------------------------------
__device__ __forceinline__ void reg_ln(float (&x)[2][4][4], float* red, float* stat,
                                       u16* xb,
                                       float gc0, float gc1, float bc0, float bc1,
                                       int tid, int wv, int col, int quad,
                                       int colg0, int colg1) {
#pragma unroll
    for (int mt = 0; mt < 4; ++mt) {
        float ps[4], pq[4];
#pragma unroll
        for (int j = 0; j < 4; ++j) {
            const float v0 = x[0][mt][j], v1 = x[1][mt][j];
            ps[j] = v0 + v1;
            pq[j] = v0 * v0 + v1 * v1;
        }
#pragma unroll
        for (int o = 1; o < 16; o <<= 1) {
#pragma unroll
            for (int j = 0; j < 4; ++j) {
                ps[j] += __shfl_xor(ps[j], o);
                pq[j] += __shfl_xor(pq[j], o);
            }
        }
        if (col == 0) {
#pragma unroll
            for (int j = 0; j < 4; ++j) {
                const int row = mt * 16 + quad * 4 + j;
                red[row * 17 + wv * 2] = ps[j];
                red[row * 17 + wv * 2 + 1] = pq[j];
            }
        }
    }
    __syncthreads();
    if (tid < 64) {
        float s = 0.f, q = 0.f;
#pragma unroll
        for (int w = 0; w < 8; ++w) {
            s += red[tid * 17 + w * 2];
            q += red[tid * 17 + w * 2 + 1];
        }
        const float m = s * 0.00390625f;
        const float var = q * 0.00390625f - m * m;
        stat[tid * 2] = m;
        stat[tid * 2 + 1] = rsqrtf(var + 1e-5f);
    }
    __syncthreads();
#pragma unroll
    for (int mt = 0; mt < 4; ++mt)
#pragma unroll
        for (int j = 0; j < 4; ++j) {
            const int row = mt * 16 + quad * 4 + j;
            const float m = stat[row * 2];
            const float rs = stat[row * 2 + 1];
            const float xn0 = (x[0][mt][j] - m) * rs * gc0 + bc0;
            const float xn1 = (x[1][mt][j] - m) * rs * gc1 + bc1;
            x[0][mt][j] = xn0;
            x[1][mt][j] = xn1;
            const u32 w = pk_bf16(xn0, xn1);
            xb[row * XBP + colg0] = (u16)w;
            xb[row * XBP + colg1] = (u16)(w >> 16);
        }
}

// ---------------------------------------------------------------------------
// k_attn: attention + deferred proj + residual + LN1 -> xbg (bf16, global)
// P has its own buffer -> 2 barriers per head-pair; next-hp gather loads are
// register-staged across barrier C (lean live set, no pacc across loop).
// ---------------------------------------------------------------------------
struct __align__(16) SMemA {
    union {
        struct { u16 qkpb[9216]; u16 vt[4608]; u16 pb[9216]; } att;  // 46,080 B
        struct { float red[64 * 17]; float stat[128]; } ln;          //  4,864 B
    } r1;
    u16 obxb[64 * XBP];   // O (attn) then xb (post-LN1)             // 33,792 B
};

__global__ __launch_bounds__(NT, 4) void k_attn(
    const float* __restrict__ emb, const u16* __restrict__ qkvp,
    const u16* __restrict__ wob, const float* __restrict__ aob,
    const float* __restrict__ ln1g, const float* __restrict__ ln1b,
    u16* __restrict__ xbg) {
    __shared__ SMemA sm;
    const int n = blockIdx.x;
    const int bb = n >> 10, p = n & 1023;
    const int tid = threadIdx.x;
    const int lane = tid & 63, wv = tid >> 6;
    const int col = lane & 15, quad = lane >> 4;
    const int colg0 = wv * 32 + col, colg1 = colg0 + 16;

    // register-staged gather for hp=0
    const int gi = tid >> 3, gdg = tid & 7;
    const u16* gbase = qkvp + ((size_t)bb * TPAD + (p + 1 + gi)) * 768 + gdg * 8;
    uint4 gq = *(const uint4*)(gbase);
    uint4 gk = *(const uint4*)(gbase + 256);
    uint4 gv = *(const uint4*)(gbase + 512);

    for (int hp = 0; hp < 4; ++hp) {
        {   // stage regs -> LDS (q,k row-major; v transposed)
            *(uint4*)(sm.r1.att.qkpb + gi * 72 + gdg * 8) = gq;
            *(uint4*)(sm.r1.att.qkpb + 4608 + gi * 72 + gdg * 8) = gk;
            union { uint4 u; u16 h[8]; } vu; vu.u = gv;
#pragma unroll
            for (int c = 0; c < 8; ++c)
                sm.r1.att.vt[(gdg * 8 + c) * 72 + gi] = vu.h[c];
        }
        __syncthreads();   // A: gather visible
        const int hh = wv >> 2, mt_ = wv & 3;
        const int r0 = mt_ * 16 + quad * 4;
        // scores MFMA + in-register softmax
        const bf8_t aq = *(const bf8_t*)(sm.r1.att.qkpb + (mt_ * 16 + col) * 72 + hh * 32 + quad * 8);
        f4_t sc[4];
#pragma unroll
        for (int nt = 0; nt < 4; ++nt) {
            const bf8_t bk = *(const bf8_t*)(sm.r1.att.qkpb + 4608 + (nt * 16 + col) * 72 + hh * 32 + quad * 8);
            f4_t z = {0.f, 0.f, 0.f, 0.f};
            sc[nt] = MFMA_B16(aq, bk, z);
        }
#pragma unroll
        for (int j = 0; j < 4; ++j) {
            float s0 = sc[0][j] * SCALE_, s1 = sc[1][j] * SCALE_;
            float s2v = sc[2][j] * SCALE_, s3 = sc[3][j] * SCALE_;
            float m = fmaxf(fmaxf(s0, s1), fmaxf(s2v, s3));
            m = fmaxf(m, __shfl_xor(m, 1)); m = fmaxf(m, __shfl_xor(m, 2));
            m = fmaxf(m, __shfl_xor(m, 4)); m = fmaxf(m, __shfl_xor(m, 8));
            const float e0 = __expf(s0 - m), e1 = __expf(s1 - m);
            const float e2 = __expf(s2v - m), e3 = __expf(s3 - m);
            float s = e0 + e1 + e2 + e3;
            s += __shfl_xor(s, 1); s += __shfl_xor(s, 2);
            s += __shfl_xor(s, 4); s += __shfl_xor(s, 8);
            const float inv = 1.f / s;
            sc[0][j] = e0 * inv; sc[1][j] = e1 * inv;
            sc[2][j] = e2 * inv; sc[3][j] = e3 * inv;
        }
        // write P to its own buffer (own-wave rows only -> no barrier needed)
        u16* pbh = sm.r1.att.pb + hh * 4608;
#pragma unroll
        for (int nt = 0; nt < 4; ++nt) {
            const u32 w01 = pk_bf16(sc[nt][0], sc[nt][1]);
            const u32 w23 = pk_bf16(sc[nt][2], sc[nt][3]);
            u16* pp = pbh + r0 * 72 + nt * 16 + col;
            pp[0] = (u16)w01; pp[72] = (u16)(w01 >> 16);
            pp[144] = (u16)w23; pp[216] = (u16)(w23 >> 16);
        }
        // PV (same-wave P rows; vt stable)
        f4_t ov[2];
        ov[0] = (f4_t){0.f, 0.f, 0.f, 0.f}; ov[1] = (f4_t){0.f, 0.f, 0.f, 0.f};
#pragma unroll
        for (int ks = 0; ks < 2; ++ks) {
            const bf8_t ap = *(const bf8_t*)(pbh + (mt_ * 16 + col) * 72 + ks * 32 + quad * 8);
#pragma unroll
            for (int ntl = 0; ntl < 2; ++ntl) {
                const bf8_t bv = *(const bf8_t*)(sm.r1.att.vt +
                                                 (hh * 32 + ntl * 16 + col) * 72 + ks * 32 + quad * 8);
                ov[ntl] = MFMA_B16(ap, bv, ov[ntl]);
            }
        }
        // issue next hp's gather loads before barrier C (fly across O-write)
        if (hp < 3) {
            const u16* gsrc = gbase + (hp + 1) * 64;
            gq = *(const uint4*)(gsrc);
            gk = *(const uint4*)(gsrc + 256);
            gv = *(const uint4*)(gsrc + 512);
        }
        // O -> full-width ob
#pragma unroll
        for (int ntl = 0; ntl < 2; ++ntl) {
            const u32 w01 = pk_bf16(ov[ntl][0], ov[ntl][1]);
            const u32 w23 = pk_bf16(ov[ntl][2], ov[ntl][3]);
            u16* oo = sm.obxb + r0 * XBP + (hp * 2 + hh) * 32 + ntl * 16 + col;
            oo[0] = (u16)w01; oo[XBP] = (u16)(w01 >> 16);
            oo[2 * XBP] = (u16)w23; oo[3 * XBP] = (u16)(w23 >> 16);
        }
        __syncthreads();   // C: q/k/vt reads done before next stage overwrites
    }

    // single proj GEMM: pacc = O @ Wo^T  (K = 256)
    f4_t pacc[2][4];
#pragma unroll
    for (int a = 0; a < 2; ++a)
#pragma unroll
        for (int m = 0; m < 4; ++m) pacc[a][m] = (f4_t){0.f, 0.f, 0.f, 0.f};
#pragma unroll 2
    for (int ks = 0; ks < 8; ++ks) {
        bf8_t ao[4];
#pragma unroll
        for (int mt = 0; mt < 4; ++mt)
            ao[mt] = *(const bf8_t*)(sm.obxb + (mt * 16 + col) * XBP + ks * 32 + quad * 8);
#pragma unroll
        for (int ntl = 0; ntl < 2; ++ntl) {
            const bf8_t bw = *(const bf8_t*)(wob + ((wv * 2 + ntl) * 16 + col) * EE_ +
                                             ks * 32 + quad * 8);
#pragma unroll
            for (int mt = 0; mt < 4; ++mt) pacc[ntl][mt] = MFMA_B16(ao[mt], bw, pacc[ntl][mt]);
        }
    }

    // combine x0 + attn + bias, LN1 -> xb in LDS
    const float aob_0 = aob[colg0], aob_1 = aob[colg1];
    float x[2][4][4];
#pragma unroll
    for (int mt = 0; mt < 4; ++mt)
#pragma unroll
        for (int j = 0; j < 4; ++j) {
            const int row = mt * 16 + quad * 4 + j;
            const int t = p - 63 + row;
            const size_t base = (size_t)((bb << 10) + t) * EE_;
            const float e0 = (t >= 0) ? emb[base + colg0] : 0.f;
            const float e1 = (t >= 0) ? emb[base + colg1] : 0.f;
            x[0][mt][j] = e0 + aob_0 + pacc[0][mt][j];
            x[1][mt][j] = e1 + aob_1 + pacc[1][mt][j];
        }
    __syncthreads();   // proj reads of ob done
    reg_ln(x, sm.r1.ln.red, sm.r1.ln.stat, sm.obxb,
           ln1g[colg0], ln1g[colg1], ln1b[colg0], ln1b[colg1],
           tid, wv, col, quad, colg0, colg1);
    __syncthreads();
    // coalesced copy-out: LDS xb (pitch 264) -> global (packed 256/row)
    u16* dst = xbg + (size_t)n * 64 * 256;
#pragma unroll
    for (int k = 0; k < 4; ++k) {
        const int idx = tid + k * NT;
        const int row = idx >> 5, seg = idx & 31;
        *(uint4*)(dst + row * 256 + seg * 8) = *(const uint4*)(sm.obxb + row * XBP + seg * 8);
    }
}

// ---------------------------------------------------------------------------
// k_mlp: FFN (double-buffered hb, merged phases, ffn1-first) + LN2 +
// layer-1 (2-hp chunks, wide sections) -> x2g. LDS ~72.7 KB (2 blk/CU).
// ---------------------------------------------------------------------------
struct __align__(16) SMemB {
    u16 xb[64 * XBP];                                            // 33,792 B
    union {
        u16 hb2[2][64 * 136];                                    // 34,816 B
        u16 kvb[4 * 64 * 66];                                    // 33,792 B
        struct { float red[64 * 17]; float stat[128]; } ln;      //  4,864 B
    } c;
    float x1row[256];
    float o1b[256];
    float q1b[256];
    float sbuf2[256];
};

__global__ __launch_bounds__(NT, 4) void k_mlp(
    const u16* __restrict__ xbg,
    const u16* __restrict__ w1b, const u16* __restrict__ w2b,
    const u16* __restrict__ wkvb, const u16* __restrict__ wq1b,
    const u16* __restrict__ wob1,
    const float* __restrict__ qkv_b, const float* __restrict__ aob,
    const float* __restrict__ f1b, const float* __restrict__ f2b,
    const float* __restrict__ ln2g, const float* __restrict__ ln2b,
    float* __restrict__ x2g) {
    __shared__ SMemB sm;
    const int n = blockIdx.x;
    const int tid = threadIdx.x;
    const int lane = tid & 63, wv = tid >> 6;
    const int col = lane & 15, quad = lane >> 4;
    const int colg0 = wv * 32 + col, colg1 = colg0 + 16;

    const float* qkv_b1 = qkv_b + 3 * EE_;
    const float* aob1p = aob + EE_;

    // load xb: global (packed) -> LDS (pitched)
    const u16* src = xbg + (size_t)n * 64 * 256;
#pragma unroll
    for (int k = 0; k < 4; ++k) {
        const int idx = tid + k * NT;
        const int row = idx >> 5, seg = idx & 31;
        *(uint4*)(sm.xb + row * XBP + seg * 8) = *(const uint4*)(src + row * 256 + seg * 8);
    }
    __syncthreads();

    // ---- FFN: double-buffered hb, merged phases (ffn1 of c+1 first)
    f4_t facc[2][4];
#pragma unroll
    for (int a = 0; a < 2; ++a)
#pragma unroll
        for (int m = 0; m < 4; ++m) facc[a][m] = (f4_t){0.f, 0.f, 0.f, 0.f};

    auto ffn1_step = [&](int c) {
        f4_t hacc[4];
#pragma unroll
        for (int m = 0; m < 4; ++m) hacc[m] = (f4_t){0.f, 0.f, 0.f, 0.f};
        const int f = c * 128 + wv * 16 + col;
#pragma unroll 2
        for (int ks = 0; ks < 8; ++ks) {
            const bf8_t bw = *(const bf8_t*)(w1b + f * EE_ + ks * 32 + quad * 8);
#pragma unroll
            for (int mt = 0; mt < 4; ++mt) {
                const bf8_t axr = *(const bf8_t*)(sm.xb + (mt * 16 + col) * XBP + ks * 32 + quad * 8);
                hacc[mt] = MFMA_B16(axr, bw, hacc[mt]);
            }
        }
        const float bv = f1b[f];
        const int lc = wv * 16 + col;
        u16* hbc = sm.c.hb2[c & 1];
#pragma unroll
        for (int mt = 0; mt < 4; ++mt) {
            const u32 w01 = pk_bf16(silu_f(hacc[mt][0] + bv), silu_f(hacc[mt][1] + bv));
            const u32 w23 = pk_bf16(silu_f(hacc[mt][2] + bv), silu_f(hacc[mt][3] + bv));
            u16* hh2 = hbc + (mt * 16 + quad * 4) * 136 + lc;
            hh2[0] = (u16)w01; hh2[136] = (u16)(w01 >> 16);
            hh2[272] = (u16)w23; hh2[408] = (u16)(w23 >> 16);
        }
    };
    auto ffn2_step = [&](int c) {
        const u16* hbc = sm.c.hb2[c & 1];
#pragma unroll 2
        for (int ks = 0; ks < 4; ++ks) {
            bf8_t ah[4];
#pragma unroll
            for (int mt = 0; mt < 4; ++mt)
                ah[mt] = *(const bf8_t*)(hbc + (mt * 16 + col) * 136 + ks * 32 + quad * 8);
#pragma unroll
            for (int ntl = 0; ntl < 2; ++ntl) {
                const int e = (wv * 2 + ntl) * 16 + col;
                const bf8_t bw = *(const bf8_t*)(w2b + e * FF_ + c * 128 + ks * 32 + quad * 8);
#pragma unroll
                for (int mt = 0; mt < 4; ++mt) facc[ntl][mt] = MFMA_B16(ah[mt], bw, facc[ntl][mt]);
            }
        }
    };

    ffn1_step(0);
    __syncthreads();
#pragma unroll 1
    for (int c = 0; c < 8; ++c) {
        if (c < 7) ffn1_step(c + 1);   // writes hb2[(c+1)&1] (loads issued early)
        ffn2_step(c);                  // reads  hb2[c&1]
        __syncthreads();
    }

    // reconstruct x from bf16 xb, add FFN2 + bias, LN2 -> x1
    const float f2b_0 = f2b[colg0], f2b_1 = f2b[colg1];
    float x[2][4][4];
#pragma unroll
    for (int mt = 0; mt < 4; ++mt)
#pragma unroll
        for (int j = 0; j < 4; ++j) {
            const int row = mt * 16 + quad * 4 + j;
            x[0][mt][j] = b2f(sm.xb[row * XBP + colg0]) + facc[0][mt][j] + f2b_0;
            x[1][mt][j] = b2f(sm.xb[row * XBP + colg1]) + facc[1][mt][j] + f2b_1;
        }
    __syncthreads();   // xb/hb reads done before reg_ln overwrites
    reg_ln(x, sm.c.ln.red, sm.c.ln.stat, sm.xb,
           ln2g[colg0], ln2g[colg1], ln2b[colg0], ln2b[colg1],
           tid, wv, col, quad, colg0, colg1);
    if (quad == 3) {   // row 63 holder: mt=3, quad=3, j=3
        sm.x1row[colg0] = x[0][3][3];
        sm.x1row[colg1] = x[1][3][3];
    }
    __syncthreads();

    // =================== Layer 1: 2 head-pairs per chunk ===================
#pragma unroll 1
    for (int chunk = 0; chunk < 2; ++chunk) {
        {   // KV MFMA for 2 hp (4 heads): wave = (hpc, hf, mtkh)
            const int hpc = wv & 1, hf = (wv >> 1) & 1, mtkh = (wv >> 2) & 1;
            const int hpg = chunk * 2 + hpc;
            f4_t kacc[2][4];
#pragma unroll
            for (int a = 0; a < 2; ++a)
#pragma unroll
                for (int b = 0; b < 4; ++b) kacc[a][b] = (f4_t){0.f, 0.f, 0.f, 0.f};
#pragma unroll 2
            for (int ks = 0; ks < 8; ++ks) {
                bf8_t ax[2];
#pragma unroll
                for (int m2 = 0; m2 < 2; ++m2)
                    ax[m2] = *(const bf8_t*)(sm.xb + ((mtkh * 2 + m2) * 16 + col) * XBP + ks * 32 + quad * 8);
#pragma unroll
                for (int nt = 0; nt < 4; ++nt) {
                    const int wr = hf * EE_ + hpg * 64 + nt * 16 + col;
                    const bf8_t bw = *(const bf8_t*)(wkvb + wr * EE_ + ks * 32 + quad * 8);
#pragma unroll
                    for (int m2 = 0; m2 < 2; ++m2) kacc[m2][nt] = MFMA_B16(ax[m2], bw, kacc[m2][nt]);
                }
            }
            u16* dst = sm.c.kvb + (hpc * 2 + hf) * 4224;
#pragma unroll
            for (int m2 = 0; m2 < 2; ++m2)
#pragma unroll
                for (int nt = 0; nt < 4; ++nt) {
                    const int cc = nt * 16 + col;
                    const float bs = qkv_b1[(hf + 1) * EE_ + hpg * 64 + cc];
                    const u32 w01 = pk_bf16(kacc[m2][nt][0] + bs, kacc[m2][nt][1] + bs);
                    const u32 w23 = pk_bf16(kacc[m2][nt][2] + bs, kacc[m2][nt][3] + bs);
                    u16* dd = dst + ((mtkh * 2 + m2) * 16 + quad * 4) * 66 + cc;
                    dd[0] = (u16)w01; dd[66] = (u16)(w01 >> 16);
                    dd[132] = (u16)w23; dd[198] = (u16)(w23 >> 16);
                }
        }
        if (chunk == 0 && tid < 256) {   // q1 for all 8 heads, one pass
            const u16* wq = wq1b + tid * EE_;
            float s = 0.f;
#pragma unroll 8
            for (int k2 = 0; k2 < 128; ++k2) {
                const u32 u = *(const u32*)(wq + k2 * 2);
                s += sm.x1row[2 * k2] * b2f_lo(u) + sm.x1row[2 * k2 + 1] * b2f_hi(u);
            }
            sm.q1b[tid] = s + qkv_b1[tid];
        }
        __syncthreads();
        if (tid < 256) {   // scores + softmax: 4 heads x 64 j (4 waves)
            const int hc = tid >> 6, jj = tid & 63;
            const int hpc = hc >> 1, hh = hc & 1;
            const u16* kr = sm.c.kvb + (hpc * 2) * 4224 + jj * 66 + hh * 32;
            const float* qv = sm.q1b + (chunk * 4 + hc) * 32;
            float s = 0.f;
#pragma unroll
            for (int d = 0; d < 32; ++d) s += qv[d] * b2f(kr[d]);
            s *= SCALE_;
            const float m = wmax(s);
            const float e = __expf(s - m);
            const float su = wsum(e);
            sm.sbuf2[hc * 64 + jj] = e / su;
        }
        __syncthreads();
        if (tid < 128) {   // o1: 4 heads x 32 d
            const int hc = tid >> 5, d = tid & 31;
            const int hpc = hc >> 1, hh = hc & 1;
            const u16* vr = sm.c.kvb + (hpc * 2 + 1) * 4224 + hh * 32 + d;
            float acc = 0.f;
            for (int j = 0; j < 64; ++j)
                acc += sm.sbuf2[hc * 64 + j] * b2f(vr[j * 66]);
            sm.o1b[(chunk * 4 + hc) * 32 + d] = acc;
        }
        __syncthreads();
    }

    // x2 = x1[63] + o1 @ Wo1^T + b  -> global
    if (tid < 256) {
        const u16* wr = wob1 + tid * EE_;
        float s = 0.f;
#pragma unroll 8
        for (int k2 = 0; k2 < 128; ++k2) {
            const u32 u = *(const u32*)(wr + k2 * 2);
            s += sm.o1b[2 * k2] * b2f_lo(u) + sm.o1b[2 * k2 + 1] * b2f_hi(u);
        }
        x2g[n * EE_ + tid] = sm.x1row[tid] + s + aob1p[tid];
    }
}

// ---------------------------------------------------------------------------
// Tail kernel: batched LN1'->FFN1'->FFN2'->LN2'->head for token 63 of all
// windows. grid = 512 blocks x 4 windows, block = 256.
// ---------------------------------------------------------------------------
__global__ __launch_bounds__(256) void k_tail(
    const float* __restrict__ x2g, const u16* __restrict__ w1b1,
    const float* __restrict__ f1b1, const u16* __restrict__ w2b1,
    const float* __restrict__ f2b1, const float* __restrict__ g1,
    const float* __restrict__ b1, const float* __restrict__ g2,
    const float* __restrict__ b2, const float* __restrict__ hw,
    const float* __restrict__ hbb, float* __restrict__ out) {
    __shared__ float xa[4 * 260];
    __shared__ float hid[4 * 1024];
    const int tid = threadIdx.x, lane = tid & 63, w = tid >> 6;
    const int n0 = blockIdx.x * 4;
    {   // LN1': one wave per window
        const float* src = x2g + (size_t)(n0 + w) * EE_;
        const float v0 = src[lane], v1 = src[lane + 64], v2 = src[lane + 128], v3 = src[lane + 192];
        const float m = wsum(v0 + v1 + v2 + v3) * 0.00390625f;
        const float d0 = v0 - m, d1 = v1 - m, d2 = v2 - m, d3 = v3 - m;
        const float var = wsum(d0 * d0 + d1 * d1 + d2 * d2 + d3 * d3) * 0.00390625f;
        const float rs = rsqrtf(var + 1e-5f);
        xa[w * 260 + lane] = d0 * rs * g1[lane] + b1[lane];
        xa[w * 260 + lane + 64] = d1 * rs * g1[lane + 64] + b1[lane + 64];
        xa[w * 260 + lane + 128] = d2 * rs * g1[lane + 128] + b1[lane + 128];
        xa[w * 260 + lane + 192] = d3 * rs * g1[lane + 192] + b1[lane + 192];
    }
    __syncthreads();
#pragma unroll 1
    for (int r = 0; r < 4; ++r) {   // FFN1
        const int f = r * 256 + tid;
        const u16* wrow = w1b1 + f * EE_;
        float a0 = 0.f, a1 = 0.f, a2 = 0.f, a3 = 0.f;
#pragma unroll 4
        for (int k2 = 0; k2 < 128; ++k2) {
            const u32 u = *(const u32*)(wrow + k2 * 2);
            const float lo = b2f_lo(u), hi = b2f_hi(u);
            const float2 h0 = *(const float2*)(xa + 0 * 260 + k2 * 2);
            const float2 h1 = *(const float2*)(xa + 1 * 260 + k2 * 2);
            const float2 h2 = *(const float2*)(xa + 2 * 260 + k2 * 2);
            const float2 h3 = *(const float2*)(xa + 3 * 260 + k2 * 2);
            a0 += h0.x * lo + h0.y * hi;
            a1 += h1.x * lo + h1.y * hi;
            a2 += h2.x * lo + h2.y * hi;
            a3 += h3.x * lo + h3.y * hi;
        }
        const float bv = f1b1[f];
        hid[0 * 1024 + f] = silu_f(a0 + bv);
        hid[1 * 1024 + f] = silu_f(a1 + bv);
        hid[2 * 1024 + f] = silu_f(a2 + bv);
        hid[3 * 1024 + f] = silu_f(a3 + bv);
    }
    __syncthreads();
    {   // FFN2
        const u16* wrow = w2b1 + tid * FF_;
        float a0 = 0.f, a1 = 0.f, a2 = 0.f, a3 = 0.f;
#pragma unroll 4
        for (int k2 = 0; k2 < 512; ++k2) {
            const u32 u = *(const u32*)(wrow + k2 * 2);
            const float lo = b2f_lo(u), hi = b2f_hi(u);
            const float2 h0 = *(const float2*)(hid + 0 * 1024 + k2 * 2);
            const float2 h1 = *(const float2*)(hid + 1 * 1024 + k2 * 2);
            const float2 h2 = *(const float2*)(hid + 2 * 1024 + k2 * 2);
            const float2 h3 = *(const float2*)(hid + 3 * 1024 + k2 * 2);
            a0 += h0.x * lo + h0.y * hi;
            a1 += h1.x * lo + h1.y * hi;
            a2 += h2.x * lo + h2.y * hi;
            a3 += h3.x * lo + h3.y * hi;
        }
        const float bv = f2b1[tid];
        const float r0 = xa[0 * 260 + tid] + a0 + bv;
        const float r1 = xa[1 * 260 + tid] + a1 + bv;
        const float r2 = xa[2 * 260 + tid] + a2 + bv;
        const float r3 = xa[3 * 260 + tid] + a3 + bv;
        __syncthreads();
        xa[0 * 260 + tid] = r0;
        xa[1 * 260 + tid] = r1;
        xa[2 * 260 + tid] = r2;
        xa[3 * 260 + tid] = r3;
    }
    __syncthreads();
    {   // LN2'
        float* row = xa + w * 260;
        const float v0 = row[lane], v1 = row[lane + 64], v2 = row[lane + 128], v3 = row[lane + 192];
        const float m = wsum(v0 + v1 + v2 + v3) * 0.00390625f;
        const float d0 = v0 - m, d1 = v1 - m, d2 = v2 - m, d3 = v3 - m;
        const float var = wsum(d0 * d0 + d1 * d1 + d2 * d2 + d3 * d3) * 0.00390625f;
        const float rs = rsqrtf(var + 1e-5f);
        __syncthreads();
        row[lane] = d0 * rs * g2[lane] + b2[lane];
        row[lane + 64] = d1 * rs * g2[lane + 64] + b2[lane + 64];
        row[lane + 128] = d2 * rs * g2[lane + 128] + b2[lane + 128];
        row[lane + 192] = d3 * rs * g2[lane + 192] + b2[lane + 192];
    }
    __syncthreads();
    if (tid < 4 * OUT_) {   // head
        const int win = tid / OUT_, o = tid % OUT_;
        const float* wr = hw + o * EE_;
        const float* xr = xa + win * 260;
        float s = 0.f;
#pragma unroll 8
        for (int c4 = 0; c4 < 64; ++c4)
            s += dot4(*(const float4*)(xr + c4 * 4), *(const float4*)(wr + c4 * 4));
        out[(n0 + win) * OUT_ + o] = s + hbb[o];
    }
}

// ---------------------------------------------------------------------------
extern "C" void kernel_launch(void* const* d_in, const int* in_sizes, int n_in,
                              void* d_out, int out_size, void* d_ws, size_t ws_size,
                              hipStream_t stream) {
    (void)in_sizes; (void)n_in; (void)out_size; (void)ws_size;
    const float* inputs = (const float*)d_in[0];
    const float* embed_w = (const float*)d_in[1];
    const float* embed_b = (const float*)d_in[2];
    const float* qkv_w = (const float*)d_in[3];
    const float* qkv_b = (const float*)d_in[4];
    const float* attn_out_w = (const float*)d_in[5];
    const float* attn_out_b = (const float*)d_in[6];
    const float* ln1_g = (const float*)d_in[7];
    const float* ln1_b = (const float*)d_in[8];
    const float* ffn1_w = (const float*)d_in[9];
    const float* ffn1_b = (const float*)d_in[10];
    const float* ffn2_w = (const float*)d_in[11];
    const float* ffn2_b = (const float*)d_in[12];
    const float* ln2_g = (const float*)d_in[13];
    const float* ln2_b = (const float*)d_in[14];
    const float* head_w = (const float*)d_in[15];
    const float* head_b = (const float*)d_in[16];
    float* out = (float*)d_out;

    char* wsb = (char*)d_ws;
    size_t off = 0;
    auto alloc = [&](size_t bytes) { char* pp = wsb + off; off += (bytes + 511) & ~511ull; return pp; };
    float* emb   = (float*)alloc((size_t)NWIN * EE_ * 4);           // 2 MB
    u16*   qkvp  = (u16*)alloc((size_t)BB_ * TPAD * 768 * 2);       // 3.34 MB
    u16*   xbg   = (u16*)alloc((size_t)NWIN * 64 * 256 * 2);        // 67 MB
    float* x2g   = (float*)alloc((size_t)NWIN * EE_ * 4);           // 2 MB
    u16*   w1b   = (u16*)alloc(FF_ * EE_ * 2);
    u16*   w2b   = (u16*)alloc(EE_ * FF_ * 2);
    u16*   wob   = (u16*)alloc(EE_ * EE_ * 2);
    u16*   wkvb  = (u16*)alloc(2 * EE_ * EE_ * 2);
    u16*   w1b1  = (u16*)alloc(FF_ * EE_ * 2);
    u16*   w2b1  = (u16*)alloc(EE_ * FF_ * 2);
    u16*   wob1  = (u16*)alloc(EE_ * EE_ * 2);
    u16*   wq1b  = (u16*)alloc(EE_ * EE_ * 2);
    u16*   wq0b  = (u16*)alloc(3 * EE_ * EE_ * 2);

    CvtArgs ca;
    ca.s[0] = ffn1_w;                            ca.d[0] = w1b;  ca.n[0] = FF_ * EE_;
    ca.s[1] = ffn2_w;                            ca.d[1] = w2b;  ca.n[1] = EE_ * FF_;
    ca.s[2] = attn_out_w;                        ca.d[2] = wob;  ca.n[2] = EE_ * EE_;
    ca.s[3] = qkv_w + 3 * EE_ * EE_ + EE_ * EE_; ca.d[3] = wkvb; ca.n[3] = 2 * EE_ * EE_;
    ca.s[4] = ffn1_w + FF_ * EE_;                ca.d[4] = w1b1; ca.n[4] = FF_ * EE_;
    ca.s[5] = ffn2_w + EE_ * FF_;                ca.d[5] = w2b1; ca.n[5] = EE_ * FF_;
    ca.s[6] = attn_out_w + EE_ * EE_;            ca.d[6] = wob1; ca.n[6] = EE_ * EE_;
    ca.s[7] = qkv_w + 3 * EE_ * EE_;             ca.d[7] = wq1b; ca.n[7] = EE_ * EE_;
    ca.s[8] = qkv_w;                             ca.d[8] = wq0b; ca.n[8] = 3 * EE_ * EE_;

    k_pre<<<2824, 256, 0, stream>>>(inputs, embed_w, embed_b, qkv_b, ca, emb, qkvp);
    k_qkv0m<<<NWIN / 16, 512, 0, stream>>>(emb, wq0b, qkv_b, qkvp);
    k_attn<<<NWIN, NT, 0, stream>>>(emb, qkvp, wob, attn_out_b, ln1_g, ln1_b, xbg);
    k_mlp<<<NWIN, NT, 0, stream>>>(xbg, w1b, w2b, wkvb, wq1b, wob1,
                                   qkv_b, attn_out_b, ffn1_b, ffn2_b,
                                   ln2_g, ln2_b, x2g);
    k_tail<<<NWIN / 4, 256, 0, stream>>>(x2g, w1b1, ffn1_b + FF_, w2b1, ffn2_b + EE_,
                                         ln1_g + EE_, ln1_b + EE_, ln2_g + EE_, ln2_b + EE_,
                                         head_w, head_b, out);
}